// Round 1
// 3164.710 us; speedup vs baseline: 4.0771x; 4.0771x over previous
//
#include <hip/hip_runtime.h>
#include <hip/hip_bf16.h>

typedef __hip_bfloat16 bf16;

#define B_    4
#define L_    4096
#define K_    12
#define H_    64
#define ZC_   780        /* MEM + K */
#define CH2_  128        /* scan chunks */
#define CL2_  32         /* rows per chunk = L_/CH2_ */
#define PSTR_ 1752       /* packed projection row: 780 Z | 768 Q | 12 G | 192 LAT */
#define QOFF_ 780
#define GOFF_ 1548
#define LOFF_ 1560

__device__ __forceinline__ float softplusf(float x){ return log1pf(__expf(x)); }
__device__ __forceinline__ float sigmoidf(float x){ return 1.f / (1.f + __expf(-x)); }

// dtype probe: score_scale == ones; f32 1.0 -> 0x3F800000
__global__ void probe_k(const unsigned* __restrict__ ss, int* __restrict__ md)
{
    if (threadIdx.x == 0 && blockIdx.x == 0) {
        unsigned w = ss[0];
        int m = 0;
        if      (w == 0x3F803F80u) m = 1;
        else if (w == 0x3C003C00u) m = 2;
        else if (w == 0x00000000u) m = 3;
        else if (w != 0x3F800000u) m = 4;
        md[0] = m;
    }
}

__global__ void fillf_k(float* __restrict__ p, long n, float v)
{
    for (long i = (long)blockIdx.x * blockDim.x + threadIdx.x; i < n;
         i += (long)gridDim.x * blockDim.x) p[i] = v;
}
__global__ void guard_k(const int* __restrict__ md, float* __restrict__ p, long n)
{
    const int m = *md;
    if (m == 0) return;
    for (long i = (long)blockIdx.x * blockDim.x + threadIdx.x; i < n;
         i += (long)gridDim.x * blockDim.x) p[i] = 4000.f + m;
}

// ---------------------------------------------------------------------------
// Tiled f32 GEMM: C[M,N] = A[M,Kd] @ B[Kd,N]. BM=BN=128, BK=16, 256 threads,
// 8x8 micro-tile with split columns (tx*4+{0..3} and +64) -> 2-way (free) LDS
// reads; [16][132] padded tiles -> conflict-free LDS stores; float4 global
// staging + float4 C stores on full tiles. Kd multiple of 16.
//   SPLIT=false: blockIdx.z = batch with element strides sA/sB/sC.
//   SPLIT=true : blockIdx.z = K-split index, chunk = kChunk (mult of 16),
//                epilogue is atomicAdd into a pre-zeroed C.
// ---------------------------------------------------------------------------
template<bool ACC, bool ATOMIC, bool SPLIT>
__global__ __launch_bounds__(256, 2) void gemm_k(
    const float* __restrict__ Ag, const float* __restrict__ Bg, float* __restrict__ Cg,
    int M, int N, int Kd, int lda, int ldb, int ldc,
    long sA, long sB, long sC, int kChunk)
{
    __shared__ float As[16][132];
    __shared__ float Bs[16][132];

    const float* A; const float* B; float* C;
    int kLo, kHi;
    if (SPLIT) {
        A = Ag; B = Bg; C = Cg;
        kLo = blockIdx.z * kChunk;
        kHi = kLo + kChunk; if (kHi > Kd) kHi = Kd;
    } else {
        A = Ag + (long)blockIdx.z * sA;
        B = Bg + (long)blockIdx.z * sB;
        C = Cg + (long)blockIdx.z * sC;
        kLo = 0; kHi = Kd;
    }
    const int m0 = blockIdx.y * 128, n0 = blockIdx.x * 128;
    const int tid = threadIdx.x;
    const int tx = tid & 15, ty = tid >> 4;
    const bool full = (m0 + 128 <= M) && (n0 + 128 <= N);
    const bool fvec = full && (((lda | ldb) & 3) == 0);

    // staging map: A: thread -> (row ar, colgrp ac); B: (row br, colgrp bc)
    const int ar = tid >> 1,  ac = (tid & 1) * 8;
    const int br = tid >> 4,  bc = (tid & 15) * 8;

    float acc[8][8];
    #pragma unroll
    for (int i = 0; i < 8; i++)
        #pragma unroll
        for (int j = 0; j < 8; j++) acc[i][j] = 0.f;

    for (int k0 = kLo; k0 < kHi; k0 += 16) {
        if (fvec) {
            const float* Ap = &A[(long)(m0 + ar) * lda + (k0 + ac)];
            const float4 av0 = *(const float4*)Ap;
            const float4 av1 = *(const float4*)(Ap + 4);
            As[ac + 0][ar] = av0.x; As[ac + 1][ar] = av0.y;
            As[ac + 2][ar] = av0.z; As[ac + 3][ar] = av0.w;
            As[ac + 4][ar] = av1.x; As[ac + 5][ar] = av1.y;
            As[ac + 6][ar] = av1.z; As[ac + 7][ar] = av1.w;
            const float* Bp = &B[(long)(k0 + br) * ldb + (n0 + bc)];
            *(float4*)&Bs[br][bc]     = *(const float4*)Bp;
            *(float4*)&Bs[br][bc + 4] = *(const float4*)(Bp + 4);
        } else {
            const int gm = m0 + ar;
            #pragma unroll
            for (int i = 0; i < 8; i++) {
                float v = 0.f;
                if (gm < M) v = A[(long)gm * lda + (k0 + ac + i)];
                As[ac + i][ar] = v;
            }
            #pragma unroll
            for (int i = 0; i < 8; i++) {
                const int gn = n0 + bc + i;
                float v = 0.f;
                if (gn < N) v = B[(long)(k0 + br) * ldb + gn];
                Bs[br][bc + i] = v;
            }
        }
        __syncthreads();
        #pragma unroll
        for (int kk = 0; kk < 16; kk++) {
            const float4 a0 = *(const float4*)&As[kk][ty * 4];
            const float4 a1 = *(const float4*)&As[kk][64 + ty * 4];
            const float4 b0 = *(const float4*)&Bs[kk][tx * 4];
            const float4 b1 = *(const float4*)&Bs[kk][64 + tx * 4];
            const float av[8] = {a0.x, a0.y, a0.z, a0.w, a1.x, a1.y, a1.z, a1.w};
            const float bv[8] = {b0.x, b0.y, b0.z, b0.w, b1.x, b1.y, b1.z, b1.w};
            #pragma unroll
            for (int i = 0; i < 8; i++)
                #pragma unroll
                for (int j = 0; j < 8; j++)
                    acc[i][j] = fmaf(av[i], bv[j], acc[i][j]);
        }
        __syncthreads();
    }

    // epilogue: row i -> m0 + (i>>2)*64 + ty*4 + (i&3); col j -> n0 + (j>>2)*64 + tx*4 + (j&3)
    if (ATOMIC) {
        #pragma unroll
        for (int i = 0; i < 8; i++) {
            const int gm = m0 + (i >> 2) * 64 + ty * 4 + (i & 3);
            if (gm >= M) continue;
            #pragma unroll
            for (int j = 0; j < 8; j++) {
                const int gn = n0 + (j >> 2) * 64 + tx * 4 + (j & 3);
                if (gn < N) atomicAdd(&C[(long)gm * ldc + gn], acc[i][j]);
            }
        }
    } else if (full && ((ldc & 3) == 0)) {
        #pragma unroll
        for (int i = 0; i < 8; i++) {
            const int gm = m0 + (i >> 2) * 64 + ty * 4 + (i & 3);
            float* Cr = C + (long)gm * ldc + n0;
            float4 v0 = make_float4(acc[i][0], acc[i][1], acc[i][2], acc[i][3]);
            float4 v1 = make_float4(acc[i][4], acc[i][5], acc[i][6], acc[i][7]);
            if (ACC) {
                const float4 o0 = *(const float4*)&Cr[tx * 4];
                const float4 o1 = *(const float4*)&Cr[64 + tx * 4];
                v0.x += o0.x; v0.y += o0.y; v0.z += o0.z; v0.w += o0.w;
                v1.x += o1.x; v1.y += o1.y; v1.z += o1.z; v1.w += o1.w;
            }
            *(float4*)&Cr[tx * 4]      = v0;
            *(float4*)&Cr[64 + tx * 4] = v1;
        }
    } else {
        #pragma unroll
        for (int i = 0; i < 8; i++) {
            const int gm = m0 + (i >> 2) * 64 + ty * 4 + (i & 3);
            if (gm >= M) continue;
            #pragma unroll
            for (int j = 0; j < 8; j++) {
                const int gn = n0 + (j >> 2) * 64 + tx * 4 + (j & 3);
                if (gn >= N) continue;
                const long cix = (long)gm * ldc + gn;
                float v = acc[i][j];
                if (ACC) v += C[cix];
                C[cix] = v;
            }
        }
    }
}

// Wup2 = W_up * highway[col/384]
__global__ void packup_k(const float* __restrict__ Wup, const float* __restrict__ hw,
                         float* __restrict__ Wup2)
{
    const int n = 192 * 4608;
    for (int i = blockIdx.x * blockDim.x + threadIdx.x; i < n;
         i += gridDim.x * blockDim.x)
        Wup2[i] = Wup[i] * hw[(i % 4608) / 384];
}

// Wall[768][1752] = [W_mem | W_q | Wg | W_dn]
__global__ void packwall_k(const float* __restrict__ Wm, const float* __restrict__ Wq,
                           const float* __restrict__ Wg_, const float* __restrict__ Wd,
                           float* __restrict__ Wall)
{
    const int n = 768 * PSTR_;
    for (int t = blockIdx.x * blockDim.x + threadIdx.x; t < n;
         t += gridDim.x * blockDim.x) {
        const int r = t / PSTR_, c = t % PSTR_;
        float v;
        if      (c < QOFF_) v = Wm[r * ZC_ + c];
        else if (c < GOFF_) v = Wq[r * 768 + (c - QOFF_)];
        else if (c < LOFF_) v = Wg_[r * 12 + (c - GOFF_)];
        else                v = Wd[r * 192 + (c - LOFF_)];
        Wall[t] = v;
    }
}

// W_ri[k][r][n]: r<64 -> W_re[k][r][n]; r>=64 -> W_im[k][r-64][n]
__global__ void packri_k(const float* __restrict__ Wre, const float* __restrict__ Wim,
                         float* __restrict__ Wri)
{
    const int n = K_ * 128 * 384;
    for (int t = blockIdx.x * blockDim.x + threadIdx.x; t < n;
         t += gridDim.x * blockDim.x) {
        const int k = t / (128 * 384);
        const int rem = t % (128 * 384);
        const int r = rem / 384, c = rem % 384;
        Wri[t] = (r < 64) ? Wre[((long)k * 64 + r) * 384 + c]
                          : Wim[((long)k * 64 + (r - 64)) * 384 + c];
    }
}

// copy Z slice of Pall into halo-offset Zs (float4; 780/4 = 195)
__global__ void zcopy_k(const float* __restrict__ P, float* __restrict__ Zs)
{
    const long n = (long)L_ * 195;
    for (long t = (long)blockIdx.x * blockDim.x + threadIdx.x; t < n;
         t += (long)gridDim.x * blockDim.x) {
        const long l = t / 195;
        const int  c = (int)(t % 195);
        ((float4*)(Zs + 3 * ZC_ + l * ZC_))[c] = ((const float4*)(P + l * PSTR_))[c];
    }
}

// ---------------------------------------------------------------------------
// Fused scan. Zs row j holds Z at l=j-3 (rows 0..2 zero halo). Pass1
// (FINAL=false): per-(chunk,k) sums into csum[k][ch][129]. Pass3 (FINAL=true):
// exclusive-prefix init, emit OUTA[l, k*128 + {h,64+h}]. Q/G read from packed
// Pall (stride PSTR_). grid (CH2_, K_), 64 threads (lane = h).
// ---------------------------------------------------------------------------
template<bool FINAL>
__global__ __launch_bounds__(64) void scan_k(
    const float* __restrict__ Zs, const float* __restrict__ P,
    const float* __restrict__ convk,
    const float* __restrict__ theta, const float* __restrict__ decay,
    const float* __restrict__ ssc, const float* __restrict__ nsc,
    const float* __restrict__ bg, float* __restrict__ csum,
    float* __restrict__ OUTA)
{
    const int ch = blockIdx.x, k = blockIdx.y, h = threadIdx.x;
    const int col = k * 64 + h, scol = 768 + k;
    const int l0 = ch * CL2_;

    const float ck0 = convk[col],  ck1 = convk[ZC_ + col];
    const float ck2 = convk[2 * ZC_ + col], ck3 = convk[3 * ZC_ + col];
    const float cs0 = convk[scol], cs1 = convk[ZC_ + scol];
    const float cs2 = convk[2 * ZC_ + scol], cs3 = convk[3 * ZC_ + scol];

    const float th    = softplusf(theta[k * 64 + h]) + 0.001f;
    const float slope = softplusf(decay[k]);
    const float sscal = ssc[k];
    const float ns    = FINAL ? nsc[k * 64 + h] : 0.f;
    const float bgk   = FINAL ? bg[k] : 0.f;
    const int   kq    = k >> 1;

    const long cb = ((long)k * CH2_ + ch) * 129;
    float dacc = 0.f, racc = 0.f, iacc = 0.f;
    if (FINAL) { dacc = csum[cb]; racc = csum[cb + 1 + h]; iacc = csum[cb + 65 + h]; }

    for (int p = 0; p < CL2_; p++) {
        const int l = l0 + p;
        const float* zr = Zs + (long)l * ZC_;
        const float kv = ck0 * zr[col]  + ck1 * zr[ZC_ + col]
                       + ck2 * zr[2 * ZC_ + col] + ck3 * zr[3 * ZC_ + col];
        const float sr = cs0 * zr[scol] + cs1 * zr[ZC_ + scol]
                       + cs2 * zr[2 * ZC_ + scol] + cs3 * zr[3 * ZC_ + scol];
        const float lp = fminf(fmaxf(sscal * sr, -20.f), 20.f);
        const float pw = __expf(lp - slope * (float)(L_ - 1 - l));
        const float phi = tanhf(kv) * th;
        float sn, cn; __sincosf(phi, &sn, &cn);
        dacc += pw; racc += kv * pw * cn; iacc += kv * pw * sn;

        if (FINAL) {
            const float invd = 1.f / fmaxf(dacc, 1e-4f);
            const float sre = racc * invd, sim = iacc * invd;
            const float qr = P[(long)l * PSTR_ + QOFF_ + (kq * 64 + h) * 2];
            const float qi = P[(long)l * PSTR_ + QOFF_ + (kq * 64 + h) * 2 + 1];
            const float gate = sigmoidf(P[(long)l * PSTR_ + GOFF_ + k] + bgk);
            const float s2 = ns * gate;
            OUTA[(long)l * 1536 + k * 128 + h]      = (sre * qr + sim * qi) * s2;
            OUTA[(long)l * 1536 + k * 128 + 64 + h] = (sim * qr - sre * qi) * s2;
        }
    }
    if (!FINAL) {
        if (h == 0) csum[cb] = dacc;
        csum[cb + 1 + h]  = racc;
        csum[cb + 65 + h] = iacc;
    }
}

// exclusive prefix over the 128 chunks, per (k, entry 0..128)
__global__ void scan2_k(float* __restrict__ csum)
{
    const int k = blockIdx.x;
    const int t = threadIdx.x;
    if (t >= 129) return;
    float run = 0.f;
    for (int c = 0; c < CH2_; c++) {
        const long ix = ((long)k * CH2_ + c) * 129 + t;
        float v = csum[ix]; csum[ix] = run; run += v;
    }
}

// ya[r, k*192+j] = yv * silu(yg), yv = Ys[r, k*384+j], yg = Ys[r, k*384+192+j]
__global__ void combine_k(const float* __restrict__ Ys, float* __restrict__ ya,
                          int rows)
{
    const long n = (long)rows * 2304;
    for (long t = (long)blockIdx.x * blockDim.x + threadIdx.x; t < n;
         t += (long)gridDim.x * blockDim.x) {
        const long r = t / 2304;
        const int cj = (int)(t % 2304);
        const int k = cj / 192, j = cj % 192;
        const long base = r * 4608 + (long)k * 384;
        const float yv = Ys[base + j];
        const float yg = Ys[base + 192 + j];
        ya[t] = yv * yg * sigmoidf(yg);
    }
}

// ---------------------------------------------------------------------------
extern "C" void kernel_launch(void* const* d_in, const int* in_sizes, int n_in,
                              void* d_out, int out_size, void* d_ws, size_t ws_size,
                              hipStream_t stream)
{
    float* out = (float*)d_out;   // f32 output (verified r8)
    const dim3 blk(256);

    // tripwire: input ordering/sizes
    const int expSz[16] = {12582912, 599040, 3120, 589824, 768, 12, 12,
                           294912, 294912, 768, 9216, 12, 147456, 884736,
                           12, 1769472};
    int bad = -1;
    if (n_in != 16) bad = 99;
    else { for (int i = 0; i < 16; i++) if (in_sizes[i] != expSz[i]) { bad = i; break; } }
    if (out_size != 12582912 && bad < 0) bad = 98;
    if (bad >= 0) {
        fillf_k<<<dim3(2048), blk, 0, stream>>>(out, out_size, 3000.f + bad);
        return;
    }

    const float* x     = (const float*)d_in[0];
    const float* W_mem = (const float*)d_in[1];
    const float* convk = (const float*)d_in[2];
    const float* W_q   = (const float*)d_in[3];
    const float* theta = (const float*)d_in[4];
    const float* decay = (const float*)d_in[5];
    const float* ssc   = (const float*)d_in[6];
    const float* W_re  = (const float*)d_in[7];
    const float* W_im  = (const float*)d_in[8];
    const float* nsc   = (const float*)d_in[9];
    const float* Wg    = (const float*)d_in[10];
    const float* bg    = (const float*)d_in[11];
    const float* W_dn  = (const float*)d_in[12];
    const float* W_up  = (const float*)d_in[13];
    const float* hw    = (const float*)d_in[14];
    const float* W_out = (const float*)d_in[15];

    // ---- workspace plan: fixed full-batch buffers + RS slab ladder
    size_t o[12];
    auto plan = [&](int Rs, size_t* oo) -> size_t {
        size_t off = 0;
        auto al = [&](size_t bytes) {
            size_t cur = off; off = (off + bytes + 255) & ~(size_t)255; return cur;
        };
        oo[0]  = al(4);                                  // md
        oo[1]  = al((size_t)K_ * CH2_ * 129 * 4);        // csum
        oo[2]  = al((size_t)(L_ + 3) * ZC_ * 4);         // Zs (3-row halo)
        oo[3]  = al((size_t)L_ * PSTR_ * 4);             // Pall (Z|Q|G|LAT)
        oo[4]  = al((size_t)L_ * 1536 * 4);              // OUTA
        oo[5]  = al((size_t)192 * 4608 * 4);             // Wup2
        oo[6]  = al((size_t)768 * PSTR_ * 4);            // Wall
        oo[7]  = al((size_t)K_ * 128 * 384 * 4);         // W_ri
        oo[8]  = al((size_t)Rs * 4608 * 4);              // Ysum slab
        oo[9]  = al((size_t)Rs * 2304 * 4);              // ya slab
        return off;
    };
    const int nCfg = 6;
    const int cfgR[nCfg] = {4096, 2048, 1024, 512, 256, 128};
    int RS = -1;
    for (int c = 0; c < nCfg; c++) {
        size_t t = plan(cfgR[c], o);
        if (t + 4096 <= ws_size) { RS = cfgR[c]; break; }
    }
    if (RS < 0) {
        fillf_k<<<dim3(2048), blk, 0, stream>>>(out, (long)out_size, 1000.f);
        return;
    }

    char* ws = (char*)d_ws;
    int*   md   = (int*)(ws + o[0]);
    float* csum = (float*)(ws + o[1]);
    float* Zs   = (float*)(ws + o[2]);
    float* Pall = (float*)(ws + o[3]);
    float* OUTA = (float*)(ws + o[4]);
    float* Wup2 = (float*)(ws + o[5]);
    float* Wall = (float*)(ws + o[6]);
    float* Wri  = (float*)(ws + o[7]);
    float* Ysum = (float*)(ws + o[8]);
    float* yap  = (float*)(ws + o[9]);

    auto cdiv = [](long a, long b) { return (int)((a + b - 1) / b); };
    auto gsz  = [&](long n) { int g = cdiv(n, 256); return g > 8192 ? 8192 : g; };

    // split-K factor for the out GEMM: target >=512 blocks; 2304/S mult of 16
    const int S = (RS >= 2048) ? 6 : (RS == 1024) ? 12 : (RS >= 256) ? 24 : 48;
    const int kChunk = 2304 / S;

    probe_k<<<dim3(1), dim3(64), 0, stream>>>((const unsigned*)ssc, md);
    packup_k<<<dim3(1024), blk, 0, stream>>>(W_up, hw, Wup2);
    packwall_k<<<dim3(1024), blk, 0, stream>>>(W_mem, W_q, Wg, W_dn, Wall);
    packri_k<<<dim3(1024), blk, 0, stream>>>(W_re, W_im, Wri);
    // zero the 3 halo rows of Zs once (never overwritten)
    fillf_k<<<dim3(16), blk, 0, stream>>>(Zs, 3 * ZC_, 0.f);

    for (int b = 0; b < B_; b++) {
        const float* xb = x + (long)b * L_ * 768;

        // one merged projection GEMM: Pall = xb @ Wall  (Z|Q|G|LAT)
        gemm_k<false, false, false><<<dim3(14, 32), blk, 0, stream>>>(
            xb, Wall, Pall, L_, PSTR_, 768, 768, PSTR_, PSTR_, 0, 0, 0, 0);
        zcopy_k<<<dim3(2048), blk, 0, stream>>>(Pall, Zs);

        // fused chunked scan (conv+elem inline), 3 passes -> OUTA
        scan_k<false><<<dim3(CH2_, K_), dim3(64), 0, stream>>>(
            Zs, nullptr, convk, theta, decay, ssc, nsc, bg, csum, nullptr);
        scan2_k<<<dim3(K_), dim3(192), 0, stream>>>(csum);
        scan_k<true><<<dim3(CH2_, K_), dim3(64), 0, stream>>>(
            Zs, Pall, convk, theta, decay, ssc, nsc, bg, csum, OUTA);

        // stages 3+4 in row slabs
        for (int r0 = 0; r0 < L_; r0 += RS) {
            // y_spec: Ysum[r, k*384+n] = OUTA[r, k*128 + 0:128] @ W_ri[k]
            gemm_k<false, false, false><<<dim3(3, RS / 128, 12), blk, 0, stream>>>(
                OUTA + (long)r0 * 1536, Wri, Ysum,
                RS, 384, 128, 1536, 384, 4608, 128, (long)128 * 384, 384, 0);
            // Ysum += LAT @ Wup2   (highway folded into Wup2)
            gemm_k<true, false, false><<<dim3(36, RS / 128), blk, 0, stream>>>(
                Pall + (long)r0 * PSTR_ + LOFF_, Wup2, Ysum,
                RS, 4608, 192, PSTR_, 4608, 4608, 0, 0, 0, 0);
            // silu combine -> ya
            combine_k<<<dim3(gsz((long)RS * 2304)), blk, 0, stream>>>(Ysum, yap, RS);
            // out = ya @ W_out (f32), split-K + atomic into zeroed slab
            float* outs = out + ((long)b * L_ + r0) * 768;
            fillf_k<<<dim3(1024), blk, 0, stream>>>(outs, (long)RS * 768, 0.f);
            gemm_k<false, true, true><<<dim3(6, RS / 128, S), blk, 0, stream>>>(
                yap, W_out, outs,
                RS, 768, 2304, 2304, 768, 768, 0, 0, 0, kChunk);
        }
    }

    guard_k<<<dim3(2048), blk, 0, stream>>>(md, out, (long)out_size);
}

// Round 2
// 2433.597 us; speedup vs baseline: 5.3020x; 1.3004x over previous
//
#include <hip/hip_runtime.h>
#include <hip/hip_bf16.h>

typedef __hip_bfloat16 bf16;

#define B_    4
#define L_    4096
#define K_    12
#define H_    64
#define ZC_   780        /* MEM + K */
#define CH2_  128        /* scan chunks */
#define CL2_  32         /* rows per chunk = L_/CH2_ */
#define PSTR_ 1752       /* packed projection row: 780 Z | 768 Q | 12 G | 192 LAT */
#define QOFF_ 780
#define GOFF_ 1548
#define LOFF_ 1560
#define SPL_  4          /* split-K factor in fallback out-GEMM (2304/4=576, %16==0) */

__device__ __forceinline__ float softplusf(float x){ return log1pf(__expf(x)); }
__device__ __forceinline__ float sigmoidf(float x){ return 1.f / (1.f + __expf(-x)); }

// dtype probe: score_scale == ones; f32 1.0 -> 0x3F800000
__global__ void probe_k(const unsigned* __restrict__ ss, int* __restrict__ md)
{
    if (threadIdx.x == 0 && blockIdx.x == 0) {
        unsigned w = ss[0];
        int m = 0;
        if      (w == 0x3F803F80u) m = 1;
        else if (w == 0x3C003C00u) m = 2;
        else if (w == 0x00000000u) m = 3;
        else if (w != 0x3F800000u) m = 4;
        md[0] = m;
    }
}

__global__ void fillf_k(float* __restrict__ p, long n, float v)
{
    for (long i = (long)blockIdx.x * blockDim.x + threadIdx.x; i < n;
         i += (long)gridDim.x * blockDim.x) p[i] = v;
}
__global__ void guard_k(const int* __restrict__ md, float* __restrict__ p, long n)
{
    const int m = *md;
    if (m == 0) return;
    for (long i = (long)blockIdx.x * blockDim.x + threadIdx.x; i < n;
         i += (long)gridDim.x * blockDim.x) p[i] = 4000.f + m;
}

// ---------------------------------------------------------------------------
// Tiled f32 GEMM: C[M,N] = A[M,Kd] @ B[Kd,N]. BM=BN=128, BK=16, 256 threads,
// 8x8 micro-tile, split columns (tx*4 and 64+tx*4), [16][132] padded LDS.
//   SPLIT=false: blockIdx.z = batch with element strides sA/sB/sC.
//   SPLIT=true : blockIdx.z = K-split index z; k range [z*kChunk, ...),
//                C offset by z*sC (private partial buffer, plain stores).
// ---------------------------------------------------------------------------
template<bool ACC, bool SPLIT>
__global__ __launch_bounds__(256, 4) void gemm_k(
    const float* __restrict__ Ag, const float* __restrict__ Bg, float* __restrict__ Cg,
    int M, int N, int Kd, int lda, int ldb, int ldc,
    long sA, long sB, long sC, int kChunk)
{
    __shared__ float As[16][132];
    __shared__ float Bs[16][132];

    const float* A; const float* B; float* C;
    int kLo, kHi;
    if (SPLIT) {
        A = Ag; B = Bg;
        C = Cg + (long)blockIdx.z * sC;
        kLo = blockIdx.z * kChunk;
        kHi = kLo + kChunk; if (kHi > Kd) kHi = Kd;
    } else {
        A = Ag + (long)blockIdx.z * sA;
        B = Bg + (long)blockIdx.z * sB;
        C = Cg + (long)blockIdx.z * sC;
        kLo = 0; kHi = Kd;
    }
    const int m0 = blockIdx.y * 128, n0 = blockIdx.x * 128;
    const int tid = threadIdx.x;
    const int tx = tid & 15, ty = tid >> 4;
    const bool full = (m0 + 128 <= M) && (n0 + 128 <= N);
    const bool fvec = full && (((lda | ldb) & 3) == 0);

    const int ar = tid >> 1,  ac = (tid & 1) * 8;
    const int br = tid >> 4,  bc = (tid & 15) * 8;

    float acc[8][8];
    #pragma unroll
    for (int i = 0; i < 8; i++)
        #pragma unroll
        for (int j = 0; j < 8; j++) acc[i][j] = 0.f;

    for (int k0 = kLo; k0 < kHi; k0 += 16) {
        if (fvec) {
            const float* Ap = &A[(long)(m0 + ar) * lda + (k0 + ac)];
            const float4 av0 = *(const float4*)Ap;
            const float4 av1 = *(const float4*)(Ap + 4);
            As[ac + 0][ar] = av0.x; As[ac + 1][ar] = av0.y;
            As[ac + 2][ar] = av0.z; As[ac + 3][ar] = av0.w;
            As[ac + 4][ar] = av1.x; As[ac + 5][ar] = av1.y;
            As[ac + 6][ar] = av1.z; As[ac + 7][ar] = av1.w;
            const float* Bp = &B[(long)(k0 + br) * ldb + (n0 + bc)];
            *(float4*)&Bs[br][bc]     = *(const float4*)Bp;
            *(float4*)&Bs[br][bc + 4] = *(const float4*)(Bp + 4);
        } else {
            const int gm = m0 + ar;
            #pragma unroll
            for (int i = 0; i < 8; i++) {
                float v = 0.f;
                if (gm < M) v = A[(long)gm * lda + (k0 + ac + i)];
                As[ac + i][ar] = v;
            }
            #pragma unroll
            for (int i = 0; i < 8; i++) {
                const int gn = n0 + bc + i;
                float v = 0.f;
                if (gn < N) v = B[(long)(k0 + br) * ldb + gn];
                Bs[br][bc + i] = v;
            }
        }
        __syncthreads();
        #pragma unroll
        for (int kk = 0; kk < 16; kk++) {
            const float4 a0 = *(const float4*)&As[kk][ty * 4];
            const float4 a1 = *(const float4*)&As[kk][64 + ty * 4];
            const float4 b0 = *(const float4*)&Bs[kk][tx * 4];
            const float4 b1 = *(const float4*)&Bs[kk][64 + tx * 4];
            const float av[8] = {a0.x, a0.y, a0.z, a0.w, a1.x, a1.y, a1.z, a1.w};
            const float bv[8] = {b0.x, b0.y, b0.z, b0.w, b1.x, b1.y, b1.z, b1.w};
            #pragma unroll
            for (int i = 0; i < 8; i++)
                #pragma unroll
                for (int j = 0; j < 8; j++)
                    acc[i][j] = fmaf(av[i], bv[j], acc[i][j]);
        }
        __syncthreads();
    }

    if (full && ((ldc & 3) == 0)) {
        #pragma unroll
        for (int i = 0; i < 8; i++) {
            const int gm = m0 + (i >> 2) * 64 + ty * 4 + (i & 3);
            float* Cr = C + (long)gm * ldc + n0;
            float4 v0 = make_float4(acc[i][0], acc[i][1], acc[i][2], acc[i][3]);
            float4 v1 = make_float4(acc[i][4], acc[i][5], acc[i][6], acc[i][7]);
            if (ACC) {
                const float4 o0 = *(const float4*)&Cr[tx * 4];
                const float4 o1 = *(const float4*)&Cr[64 + tx * 4];
                v0.x += o0.x; v0.y += o0.y; v0.z += o0.z; v0.w += o0.w;
                v1.x += o1.x; v1.y += o1.y; v1.z += o1.z; v1.w += o1.w;
            }
            *(float4*)&Cr[tx * 4]      = v0;
            *(float4*)&Cr[64 + tx * 4] = v1;
        }
    } else {
        #pragma unroll
        for (int i = 0; i < 8; i++) {
            const int gm = m0 + (i >> 2) * 64 + ty * 4 + (i & 3);
            if (gm >= M) continue;
            #pragma unroll
            for (int j = 0; j < 8; j++) {
                const int gn = n0 + (j >> 2) * 64 + tx * 4 + (j & 3);
                if (gn >= N) continue;
                const long cix = (long)gm * ldc + gn;
                float v = acc[i][j];
                if (ACC) v += C[cix];
                C[cix] = v;
            }
        }
    }
}

// ---------------------------------------------------------------------------
// Fused stage 3+4: for a 128x128 tile of the (row, interleaved-Ysum-col) space,
// acc = OUTA[:,k*128:+128] @ Wri2[k]  (Kd=128)
//     + LAT @ Wup3                    (Kd=192),
// where columns are interleaved (yv,yg) pairs; epilogue writes
// ya[r, k*192+j] = yv * yg * sigmoid(yg) directly. Grid (36, Mrows/128).
// All tiles full; all strides %4 == 0.
// ---------------------------------------------------------------------------
__global__ __launch_bounds__(256, 4) void stage34_k(
    const float* __restrict__ OUTA, const float* __restrict__ Pall,
    const float* __restrict__ Wri2, const float* __restrict__ Wup3,
    float* __restrict__ ya)
{
    __shared__ float As[16][132];
    __shared__ float Bs[16][132];

    const int n0 = blockIdx.x * 128, m0 = blockIdx.y * 128;
    const int k  = n0 / 384;
    const int tid = threadIdx.x;
    const int tx = tid & 15, ty = tid >> 4;
    const int ar = tid >> 1,  ac = (tid & 1) * 8;
    const int br = tid >> 4,  bc = (tid & 15) * 8;

    float acc[8][8];
    #pragma unroll
    for (int i = 0; i < 8; i++)
        #pragma unroll
        for (int j = 0; j < 8; j++) acc[i][j] = 0.f;

    // ---- phase 1: OUTA(:, k*128 : k*128+128) @ Wri2[k] (128 x 384 block)
    {
        const float* A1 = OUTA + (long)(m0 + ar) * 1536 + k * 128 + ac;
        const float* B1 = Wri2 + (long)k * 128 * 384 + (n0 - k * 384) + bc;
        for (int k0 = 0; k0 < 128; k0 += 16) {
            const float4 av0 = *(const float4*)(A1 + k0);
            const float4 av1 = *(const float4*)(A1 + k0 + 4);
            As[ac + 0][ar] = av0.x; As[ac + 1][ar] = av0.y;
            As[ac + 2][ar] = av0.z; As[ac + 3][ar] = av0.w;
            As[ac + 4][ar] = av1.x; As[ac + 5][ar] = av1.y;
            As[ac + 6][ar] = av1.z; As[ac + 7][ar] = av1.w;
            const float* Bp = B1 + (long)(k0 + br) * 384;
            *(float4*)&Bs[br][bc]     = *(const float4*)Bp;
            *(float4*)&Bs[br][bc + 4] = *(const float4*)(Bp + 4);
            __syncthreads();
            #pragma unroll
            for (int kk = 0; kk < 16; kk++) {
                const float4 a0 = *(const float4*)&As[kk][ty * 4];
                const float4 a1 = *(const float4*)&As[kk][64 + ty * 4];
                const float4 b0 = *(const float4*)&Bs[kk][tx * 4];
                const float4 b1 = *(const float4*)&Bs[kk][64 + tx * 4];
                const float av[8] = {a0.x, a0.y, a0.z, a0.w, a1.x, a1.y, a1.z, a1.w};
                const float bv[8] = {b0.x, b0.y, b0.z, b0.w, b1.x, b1.y, b1.z, b1.w};
                #pragma unroll
                for (int i = 0; i < 8; i++)
                    #pragma unroll
                    for (int j = 0; j < 8; j++)
                        acc[i][j] = fmaf(av[i], bv[j], acc[i][j]);
            }
            __syncthreads();
        }
    }
    // ---- phase 2: LAT (Pall cols LOFF_..+192) @ Wup3 (192 x 4608)
    {
        const float* A2 = Pall + (long)(m0 + ar) * PSTR_ + LOFF_ + ac;
        const float* B2 = Wup3 + n0 + bc;
        for (int k0 = 0; k0 < 192; k0 += 16) {
            const float4 av0 = *(const float4*)(A2 + k0);
            const float4 av1 = *(const float4*)(A2 + k0 + 4);
            As[ac + 0][ar] = av0.x; As[ac + 1][ar] = av0.y;
            As[ac + 2][ar] = av0.z; As[ac + 3][ar] = av0.w;
            As[ac + 4][ar] = av1.x; As[ac + 5][ar] = av1.y;
            As[ac + 6][ar] = av1.z; As[ac + 7][ar] = av1.w;
            const float* Bp = B2 + (long)(k0 + br) * 4608;
            *(float4*)&Bs[br][bc]     = *(const float4*)Bp;
            *(float4*)&Bs[br][bc + 4] = *(const float4*)(Bp + 4);
            __syncthreads();
            #pragma unroll
            for (int kk = 0; kk < 16; kk++) {
                const float4 a0 = *(const float4*)&As[kk][ty * 4];
                const float4 a1 = *(const float4*)&As[kk][64 + ty * 4];
                const float4 b0 = *(const float4*)&Bs[kk][tx * 4];
                const float4 b1 = *(const float4*)&Bs[kk][64 + tx * 4];
                const float av[8] = {a0.x, a0.y, a0.z, a0.w, a1.x, a1.y, a1.z, a1.w};
                const float bv[8] = {b0.x, b0.y, b0.z, b0.w, b1.x, b1.y, b1.z, b1.w};
                #pragma unroll
                for (int i = 0; i < 8; i++)
                    #pragma unroll
                    for (int j = 0; j < 8; j++)
                        acc[i][j] = fmaf(av[i], bv[j], acc[i][j]);
            }
            __syncthreads();
        }
    }

    // ---- epilogue: interleaved pairs -> ya = yv * silu(yg)
    const int yab = k * 192 + (n0 - k * 384) / 2;
    #pragma unroll
    for (int i = 0; i < 8; i++) {
        const int gm = m0 + (i >> 2) * 64 + ty * 4 + (i & 3);
        const float g0 = acc[i][1], g1 = acc[i][3], g2 = acc[i][5], g3 = acc[i][7];
        float2 r01, r23;
        r01.x = acc[i][0] * g0 * sigmoidf(g0);
        r01.y = acc[i][2] * g1 * sigmoidf(g1);
        r23.x = acc[i][4] * g2 * sigmoidf(g2);
        r23.y = acc[i][6] * g3 * sigmoidf(g3);
        float* yr = ya + (long)gm * 2304 + yab;
        *(float2*)&yr[tx * 2]      = r01;
        *(float2*)&yr[32 + tx * 2] = r23;
    }
}

// partial-sum reduction: out[i] = sum_{z<SPL_} P[z*q + i], float4-wide
__global__ void reduce4_k(const float4* __restrict__ P, float4* __restrict__ O,
                          long n4, long q4)
{
    for (long t = (long)blockIdx.x * blockDim.x + threadIdx.x; t < n4;
         t += (long)gridDim.x * blockDim.x) {
        float4 a = P[t];
        #pragma unroll
        for (int z = 1; z < SPL_; z++) {
            const float4 b = P[t + (long)z * q4];
            a.x += b.x; a.y += b.y; a.z += b.z; a.w += b.w;
        }
        O[t] = a;
    }
}

// Wall[768][1752] = [W_mem | W_q | Wg | W_dn]
__global__ void packwall_k(const float* __restrict__ Wm, const float* __restrict__ Wq,
                           const float* __restrict__ Wg_, const float* __restrict__ Wd,
                           float* __restrict__ Wall)
{
    const int n = 768 * PSTR_;
    for (int t = blockIdx.x * blockDim.x + threadIdx.x; t < n;
         t += gridDim.x * blockDim.x) {
        const int r = t / PSTR_, c = t % PSTR_;
        float v;
        if      (c < QOFF_) v = Wm[r * ZC_ + c];
        else if (c < GOFF_) v = Wq[r * 768 + (c - QOFF_)];
        else if (c < LOFF_) v = Wg_[r * 12 + (c - GOFF_)];
        else                v = Wd[r * 192 + (c - LOFF_)];
        Wall[t] = v;
    }
}

// Wri2[k][r][2j+s] = (r<64 ? W_re[k][r][.] : W_im[k][r-64][.]) at src col j+192s
__global__ void packri2_k(const float* __restrict__ Wre, const float* __restrict__ Wim,
                          float* __restrict__ Wri2)
{
    const int n = K_ * 128 * 384;
    for (int t = blockIdx.x * blockDim.x + threadIdx.x; t < n;
         t += gridDim.x * blockDim.x) {
        const int k = t / (128 * 384);
        const int rem = t % (128 * 384);
        const int r = rem / 384, cp = rem % 384;
        const int src = (cp >> 1) + 192 * (cp & 1);
        Wri2[t] = (r < 64) ? Wre[((long)k * 64 + r) * 384 + src]
                           : Wim[((long)k * 64 + (r - 64)) * 384 + src];
    }
}

// Wup3[r][k*384 + 2j+s] = W_up[r][k*384 + j + 192s] * hw[k]
__global__ void packup3_k(const float* __restrict__ Wup, const float* __restrict__ hw,
                          float* __restrict__ Wup3)
{
    const int n = 192 * 4608;
    for (int t = blockIdx.x * blockDim.x + threadIdx.x; t < n;
         t += gridDim.x * blockDim.x) {
        const int r = t / 4608, c = t % 4608;
        const int k = c / 384, cp = c % 384;
        const int src = (cp >> 1) + 192 * (cp & 1);
        Wup3[t] = Wup[r * 4608 + k * 384 + src] * hw[k];
    }
}

// ---------------------------------------------------------------------------
// Fused scan, reading Z directly from Pall (cols 0..779, guarded 3-row halo).
// Pass1 (FINAL=false): per-(chunk,k) sums into csum[k][ch][129].
// Pass3 (FINAL=true): exclusive-prefix init, emit OUTA[l, k*128 + {h,64+h}].
// grid (CH2_, K_), 64 threads (lane = h).
// ---------------------------------------------------------------------------
template<bool FINAL>
__global__ __launch_bounds__(64) void scan_k(
    const float* __restrict__ P, const float* __restrict__ convk,
    const float* __restrict__ theta, const float* __restrict__ decay,
    const float* __restrict__ ssc, const float* __restrict__ nsc,
    const float* __restrict__ bg, float* __restrict__ csum,
    float* __restrict__ OUTA)
{
    const int ch = blockIdx.x, k = blockIdx.y, h = threadIdx.x;
    const int col = k * 64 + h, scol = 768 + k;
    const int l0 = ch * CL2_;

    const float ck0 = convk[col],  ck1 = convk[ZC_ + col];
    const float ck2 = convk[2 * ZC_ + col], ck3 = convk[3 * ZC_ + col];
    const float cs0 = convk[scol], cs1 = convk[ZC_ + scol];
    const float cs2 = convk[2 * ZC_ + scol], cs3 = convk[3 * ZC_ + scol];

    const float th    = softplusf(theta[k * 64 + h]) + 0.001f;
    const float slope = softplusf(decay[k]);
    const float sscal = ssc[k];
    const float ns    = FINAL ? nsc[k * 64 + h] : 0.f;
    const float bgk   = FINAL ? bg[k] : 0.f;
    const int   kq    = k >> 1;

    const long cb = ((long)k * CH2_ + ch) * 129;
    float dacc = 0.f, racc = 0.f, iacc = 0.f;
    if (FINAL) { dacc = csum[cb]; racc = csum[cb + 1 + h]; iacc = csum[cb + 65 + h]; }

    for (int p = 0; p < CL2_; p++) {
        const int l = l0 + p;
        float kv, sr;
        if (l >= 3) {   // fast path: all 4 conv taps in-range
            const float* zb = P + (long)(l - 3) * PSTR_;
            kv = ck0 * zb[col]  + ck1 * zb[PSTR_ + col]
               + ck2 * zb[2 * PSTR_ + col] + ck3 * zb[3 * PSTR_ + col];
            sr = cs0 * zb[scol] + cs1 * zb[PSTR_ + scol]
               + cs2 * zb[2 * PSTR_ + scol] + cs3 * zb[3 * PSTR_ + scol];
        } else {        // halo rows (chunk 0 only)
            kv = ck3 * P[(long)l * PSTR_ + col];
            sr = cs3 * P[(long)l * PSTR_ + scol];
            if (l >= 1) { kv += ck2 * P[(long)(l - 1) * PSTR_ + col];
                          sr += cs2 * P[(long)(l - 1) * PSTR_ + scol]; }
            if (l >= 2) { kv += ck1 * P[(long)(l - 2) * PSTR_ + col];
                          sr += cs1 * P[(long)(l - 2) * PSTR_ + scol]; }
        }
        const float lp = fminf(fmaxf(sscal * sr, -20.f), 20.f);
        const float pw = __expf(lp - slope * (float)(L_ - 1 - l));
        const float phi = tanhf(kv) * th;
        float sn, cn; __sincosf(phi, &sn, &cn);
        dacc += pw; racc += kv * pw * cn; iacc += kv * pw * sn;

        if (FINAL) {
            const float invd = 1.f / fmaxf(dacc, 1e-4f);
            const float sre = racc * invd, sim = iacc * invd;
            const float qr = P[(long)l * PSTR_ + QOFF_ + (kq * 64 + h) * 2];
            const float qi = P[(long)l * PSTR_ + QOFF_ + (kq * 64 + h) * 2 + 1];
            const float gate = sigmoidf(P[(long)l * PSTR_ + GOFF_ + k] + bgk);
            const float s2 = ns * gate;
            OUTA[(long)l * 1536 + k * 128 + h]      = (sre * qr + sim * qi) * s2;
            OUTA[(long)l * 1536 + k * 128 + 64 + h] = (sim * qr - sre * qi) * s2;
        }
    }
    if (!FINAL) {
        if (h == 0) csum[cb] = dacc;
        csum[cb + 1 + h]  = racc;
        csum[cb + 65 + h] = iacc;
    }
}

// exclusive prefix over the 128 chunks, per (k, entry 0..128)
__global__ void scan2_k(float* __restrict__ csum)
{
    const int k = blockIdx.x;
    const int t = threadIdx.x;
    if (t >= 129) return;
    float run = 0.f;
    for (int c = 0; c < CH2_; c++) {
        const long ix = ((long)k * CH2_ + c) * 129 + t;
        float v = csum[ix]; csum[ix] = run; run += v;
    }
}

// ---------------------------------------------------------------------------
extern "C" void kernel_launch(void* const* d_in, const int* in_sizes, int n_in,
                              void* d_out, int out_size, void* d_ws, size_t ws_size,
                              hipStream_t stream)
{
    float* out = (float*)d_out;   // f32 output (verified r8)
    const dim3 blk(256);

    // tripwire: input ordering/sizes
    const int expSz[16] = {12582912, 599040, 3120, 589824, 768, 12, 12,
                           294912, 294912, 768, 9216, 12, 147456, 884736,
                           12, 1769472};
    int bad = -1;
    if (n_in != 16) bad = 99;
    else { for (int i = 0; i < 16; i++) if (in_sizes[i] != expSz[i]) { bad = i; break; } }
    if (out_size != 12582912 && bad < 0) bad = 98;
    if (bad >= 0) {
        fillf_k<<<dim3(2048), blk, 0, stream>>>(out, out_size, 3000.f + bad);
        return;
    }

    const float* x     = (const float*)d_in[0];
    const float* W_mem = (const float*)d_in[1];
    const float* convk = (const float*)d_in[2];
    const float* W_q   = (const float*)d_in[3];
    const float* theta = (const float*)d_in[4];
    const float* decay = (const float*)d_in[5];
    const float* ssc   = (const float*)d_in[6];
    const float* W_re  = (const float*)d_in[7];
    const float* W_im  = (const float*)d_in[8];
    const float* nsc   = (const float*)d_in[9];
    const float* Wg    = (const float*)d_in[10];
    const float* bg    = (const float*)d_in[11];
    const float* W_dn  = (const float*)d_in[12];
    const float* W_up  = (const float*)d_in[13];
    const float* hw    = (const float*)d_in[14];
    const float* W_out = (const float*)d_in[15];

    // ---- workspace plan: cfg0 = full-batch ya (single big out-GEMM, no split);
    //      fallback = per-slab ya + split-K partial buffers + reduce.
    size_t o[10];
    auto plan = [&](int Rs, bool yaAll, size_t* oo) -> size_t {
        size_t off = 0;
        auto al = [&](size_t bytes) {
            size_t cur = off; off = (off + bytes + 255) & ~(size_t)255; return cur;
        };
        oo[0] = al(4);                                   // md
        oo[1] = al((size_t)K_ * CH2_ * 129 * 4);         // csum
        oo[2] = al((size_t)L_ * PSTR_ * 4);              // Pall (Z|Q|G|LAT)
        oo[3] = al((size_t)L_ * 1536 * 4);               // OUTA
        oo[4] = al((size_t)192 * 4608 * 4);              // Wup3
        oo[5] = al((size_t)768 * PSTR_ * 4);             // Wall
        oo[6] = al((size_t)K_ * 128 * 384 * 4);          // Wri2
        oo[7] = al(yaAll ? (size_t)B_ * L_ * 2304 * 4
                         : (size_t)Rs * 2304 * 4);       // ya
        oo[8] = al(yaAll ? 0 : (size_t)SPL_ * Rs * 768 * 4); // outP
        return off;
    };
    const int nCfg = 6;
    const int  cfgR[nCfg] = {4096, 4096, 2048, 1024, 512, 256};
    const bool cfgA[nCfg] = {true, false, false, false, false, false};
    int RS = -1; bool YAALL = false;
    for (int c = 0; c < nCfg; c++) {
        size_t t = plan(cfgR[c], cfgA[c], o);
        if (t + 4096 <= ws_size) { RS = cfgR[c]; YAALL = cfgA[c]; break; }
    }
    if (RS < 0) {
        fillf_k<<<dim3(2048), blk, 0, stream>>>(out, (long)out_size, 1000.f);
        return;
    }

    char* ws = (char*)d_ws;
    int*   md   = (int*)(ws + o[0]);
    float* csum = (float*)(ws + o[1]);
    float* Pall = (float*)(ws + o[2]);
    float* OUTA = (float*)(ws + o[3]);
    float* Wup3 = (float*)(ws + o[4]);
    float* Wall = (float*)(ws + o[5]);
    float* Wri2 = (float*)(ws + o[6]);
    float* yab  = (float*)(ws + o[7]);
    float* outP = (float*)(ws + o[8]);

    auto cdiv = [](long a, long b) { return (int)((a + b - 1) / b); };
    auto gsz  = [&](long n) { int g = cdiv(n, 256); return g > 8192 ? 8192 : g; };

    probe_k<<<dim3(1), dim3(64), 0, stream>>>((const unsigned*)ssc, md);
    packwall_k<<<dim3(1024), blk, 0, stream>>>(W_mem, W_q, Wg, W_dn, Wall);
    packri2_k<<<dim3(1024), blk, 0, stream>>>(W_re, W_im, Wri2);
    packup3_k<<<dim3(1024), blk, 0, stream>>>(W_up, hw, Wup3);

    for (int b = 0; b < B_; b++) {
        const float* xb = x + (long)b * L_ * 768;

        // merged projection GEMM: Pall = xb @ Wall  (Z|Q|G|LAT)
        gemm_k<false, false><<<dim3(14, 32), blk, 0, stream>>>(
            xb, Wall, Pall, L_, PSTR_, 768, 768, PSTR_, PSTR_, 0, 0, 0, 0);

        // fused chunked scan (conv+elem inline), 3 passes -> OUTA
        scan_k<false><<<dim3(CH2_, K_), dim3(64), 0, stream>>>(
            Pall, convk, theta, decay, ssc, nsc, bg, csum, nullptr);
        scan2_k<<<dim3(K_), dim3(192), 0, stream>>>(csum);
        scan_k<true><<<dim3(CH2_, K_), dim3(64), 0, stream>>>(
            Pall, convk, theta, decay, ssc, nsc, bg, csum, OUTA);

        // fused stage 3+4 -> ya (no Ysum, no combine)
        for (int r0 = 0; r0 < L_; r0 += RS) {
            float* yaDst = YAALL ? yab + ((long)b * L_ + r0) * 2304
                                 : yab;
            stage34_k<<<dim3(36, RS / 128), blk, 0, stream>>>(
                OUTA + (long)r0 * 1536, Pall + (long)r0 * PSTR_,
                Wri2, Wup3, yaDst);

            if (!YAALL) {
                // out = ya @ W_out via split-K partials + reduce (no atomics)
                gemm_k<false, true><<<dim3(6, RS / 128, SPL_), blk, 0, stream>>>(
                    yab, W_out, outP,
                    RS, 768, 2304, 2304, 768, 768, 0, 0, (long)RS * 768,
                    2304 / SPL_);
                reduce4_k<<<dim3(gsz((long)RS * 768 / 4)), blk, 0, stream>>>(
                    (const float4*)outP,
                    (float4*)(out + ((long)b * L_ + r0) * 768),
                    (long)RS * 768 / 4, (long)RS * 768 / 4);
            }
        }
    }

    if (YAALL) {
        // one big out-GEMM over all batches: (B*L) x 768, Kd=2304
        gemm_k<false, false><<<dim3(6, (B_ * L_) / 128), blk, 0, stream>>>(
            yab, W_out, out, B_ * L_, 768, 2304, 2304, 768, 768, 0, 0, 0, 0);
    }

    guard_k<<<dim3(2048), blk, 0, stream>>>(md, out, (long)out_size);
}

// Round 3
// 1172.982 us; speedup vs baseline: 11.0002x; 2.0747x over previous
//
#include <hip/hip_runtime.h>

typedef __attribute__((ext_vector_type(8))) __bf16 bf16x8;
typedef __attribute__((ext_vector_type(4))) float f32x4;

#define B_    4
#define L_    4096
#define K_    12
#define ZC_   780        /* MEM + K */
#define CH2_  128        /* scan chunks */
#define CL2_  32         /* rows per chunk = L_/CH2_ */
#define PSTR_ 1752       /* packed projection row: 780 Z | 768 Q | 12 G | 192 LAT */
#define QOFF_ 780
#define GOFF_ 1548
#define LOFF_ 1560

__device__ __forceinline__ float softplusf(float x){ return log1pf(__expf(x)); }
__device__ __forceinline__ float sigmoidf(float x){ return 1.f / (1.f + __expf(-x)); }
// f32 -> bf16 RNE (no NaN/Inf expected in this model)
__device__ __forceinline__ unsigned short f2bf(float x){
    unsigned u = __float_as_uint(x);
    u += 0x7FFFu + ((u >> 16) & 1u);
    return (unsigned short)(u >> 16);
}
__device__ __forceinline__ float bf2f(unsigned short h){
    return __uint_as_float((unsigned)h << 16);
}

// dtype probe: score_scale == ones; f32 1.0 -> 0x3F800000
__global__ void probe_k(const unsigned* __restrict__ ss, int* __restrict__ md)
{
    if (threadIdx.x == 0 && blockIdx.x == 0) {
        unsigned w = ss[0];
        int m = 0;
        if      (w == 0x3F803F80u) m = 1;
        else if (w == 0x3C003C00u) m = 2;
        else if (w == 0x00000000u) m = 3;
        else if (w != 0x3F800000u) m = 4;
        md[0] = m;
    }
}

__global__ void fillf_k(float* __restrict__ p, long n, float v)
{
    for (long i = (long)blockIdx.x * blockDim.x + threadIdx.x; i < n;
         i += (long)gridDim.x * blockDim.x) p[i] = v;
}
__global__ void guard_k(const int* __restrict__ md, float* __restrict__ p, long n)
{
    const int m = *md;
    if (m == 0) return;
    for (long i = (long)blockIdx.x * blockDim.x + threadIdx.x; i < n;
         i += (long)gridDim.x * blockDim.x) p[i] = 4000.f + m;
}

// ---------------------------------------------------------------------------
// Split-bf16 MFMA GEMM: C[M,N] = A[M,Kd] @ B[Kd,N] in ~f32 precision via
// A_hi@B_hi + A_hi@B_lo + A_lo@B_hi (each value split into 2 bf16).
// BM=BN=128, BK=32, 256 threads = 4 waves (2x2), 64x64 per wave,
// 16 x mfma_f32_16x16x32_bf16 fragments per wave per part.
// B is pre-packed transposed hi/lo: Bp[n][2*Kd] = [hi(0..Kd-1) | lo(0..Kd-1)],
// n padded to a multiple of 128. A is f32 (converted during staging) when
// AT=float, or pre-packed like B when AT=unsigned short (lda in ushorts).
// M must be a multiple of 128; Kd a multiple of 32.
// ---------------------------------------------------------------------------
template<typename AT>
__global__ __launch_bounds__(256, 2) void gemmx_k(
    const AT* __restrict__ A, const unsigned short* __restrict__ Bp,
    float* __restrict__ C, int N, int Kd, int lda, int ldc)
{
    __shared__ unsigned short As[128][72];   // [m][0..31]=hi, [32..63]=lo
    __shared__ unsigned short Bs[128][72];   // [n][0..31]=hi, [32..63]=lo
    constexpr bool APK = (sizeof(AT) == 2);

    const int n0 = blockIdx.x * 128, m0 = blockIdx.y * 128;
    const int tid  = threadIdx.x;
    const int lane = tid & 63, wave = tid >> 6;
    const int wm = (wave >> 1) * 64, wn = (wave & 1) * 64;
    const int lr = lane & 15, lg = lane >> 4;
    const int sar = tid >> 1,  sac = (tid & 1) * 16;   // f32-A staging map
    const int sbr = tid & 127, sbp = tid >> 7;         // packed staging map

    f32x4 acc[4][4];
    #pragma unroll
    for (int i = 0; i < 4; i++)
        #pragma unroll
        for (int j = 0; j < 4; j++) acc[i][j] = (f32x4){0.f, 0.f, 0.f, 0.f};

    const int ldb = 2 * Kd;

    for (int k0 = 0; k0 < Kd; k0 += 32) {
        if constexpr (APK) {
            const unsigned short* Aq = A + (long)(m0 + sbr) * lda + sbp * Kd + k0;
            uint4 u0 = *(const uint4*)(Aq);
            uint4 u1 = *(const uint4*)(Aq + 8);
            uint4 u2 = *(const uint4*)(Aq + 16);
            uint4 u3 = *(const uint4*)(Aq + 24);
            *(uint4*)&As[sbr][sbp * 32 + 0]  = u0;
            *(uint4*)&As[sbr][sbp * 32 + 8]  = u1;
            *(uint4*)&As[sbr][sbp * 32 + 16] = u2;
            *(uint4*)&As[sbr][sbp * 32 + 24] = u3;
        } else {
            const float* Ap = (const float*)A + (long)(m0 + sar) * lda + (k0 + sac);
            const float4 f0 = *(const float4*)(Ap + 0);
            const float4 f1 = *(const float4*)(Ap + 4);
            const float4 f2 = *(const float4*)(Ap + 8);
            const float4 f3 = *(const float4*)(Ap + 12);
            const float v[16] = {f0.x,f0.y,f0.z,f0.w, f1.x,f1.y,f1.z,f1.w,
                                 f2.x,f2.y,f2.z,f2.w, f3.x,f3.y,f3.z,f3.w};
            unsigned hp[8], lp[8];
            #pragma unroll
            for (int q = 0; q < 8; q++) {
                const float a = v[2*q], b = v[2*q+1];
                const unsigned short ha = f2bf(a), hb = f2bf(b);
                const unsigned short la = f2bf(a - bf2f(ha));
                const unsigned short lb = f2bf(b - bf2f(hb));
                hp[q] = (unsigned)ha | ((unsigned)hb << 16);
                lp[q] = (unsigned)la | ((unsigned)lb << 16);
            }
            *(uint4*)&As[sar][sac]          = make_uint4(hp[0],hp[1],hp[2],hp[3]);
            *(uint4*)&As[sar][sac + 8]      = make_uint4(hp[4],hp[5],hp[6],hp[7]);
            *(uint4*)&As[sar][32 + sac]     = make_uint4(lp[0],lp[1],lp[2],lp[3]);
            *(uint4*)&As[sar][32 + sac + 8] = make_uint4(lp[4],lp[5],lp[6],lp[7]);
        }
        {
            const unsigned short* Bq = Bp + (long)(n0 + sbr) * ldb + sbp * Kd + k0;
            uint4 u0 = *(const uint4*)(Bq);
            uint4 u1 = *(const uint4*)(Bq + 8);
            uint4 u2 = *(const uint4*)(Bq + 16);
            uint4 u3 = *(const uint4*)(Bq + 24);
            *(uint4*)&Bs[sbr][sbp * 32 + 0]  = u0;
            *(uint4*)&Bs[sbr][sbp * 32 + 8]  = u1;
            *(uint4*)&Bs[sbr][sbp * 32 + 16] = u2;
            *(uint4*)&Bs[sbr][sbp * 32 + 24] = u3;
        }
        __syncthreads();
        bf16x8 af[4], bh[4], bl[4];
        #pragma unroll
        for (int f = 0; f < 4; f++) {
            af[f] = *(const bf16x8*)&As[wm + f * 16 + lr][lg * 8];
            bh[f] = *(const bf16x8*)&Bs[wn + f * 16 + lr][lg * 8];
            bl[f] = *(const bf16x8*)&Bs[wn + f * 16 + lr][32 + lg * 8];
        }
        #pragma unroll
        for (int i = 0; i < 4; i++)
            #pragma unroll
            for (int j = 0; j < 4; j++)
                acc[i][j] = __builtin_amdgcn_mfma_f32_16x16x32_bf16(af[i], bh[j], acc[i][j], 0, 0, 0);
        #pragma unroll
        for (int i = 0; i < 4; i++)
            #pragma unroll
            for (int j = 0; j < 4; j++)
                acc[i][j] = __builtin_amdgcn_mfma_f32_16x16x32_bf16(af[i], bl[j], acc[i][j], 0, 0, 0);
        #pragma unroll
        for (int f = 0; f < 4; f++)
            af[f] = *(const bf16x8*)&As[wm + f * 16 + lr][32 + lg * 8];
        #pragma unroll
        for (int i = 0; i < 4; i++)
            #pragma unroll
            for (int j = 0; j < 4; j++)
                acc[i][j] = __builtin_amdgcn_mfma_f32_16x16x32_bf16(af[i], bh[j], acc[i][j], 0, 0, 0);
        __syncthreads();
    }

    // D layout: col = lane&15, row = (lane>>4)*4 + reg
    #pragma unroll
    for (int i = 0; i < 4; i++) {
        #pragma unroll
        for (int j = 0; j < 4; j++) {
            const int gn = n0 + wn + j * 16 + lr;
            if (gn < N) {
                #pragma unroll
                for (int r = 0; r < 4; r++) {
                    const int gm = m0 + wm + i * 16 + lg * 4 + r;
                    C[(long)gm * ldc + gn] = acc[i][j][r];
                }
            }
        }
    }
}

// ---------------------------------------------------------------------------
// Fused stage 3+4 (MFMA, split-bf16): per 128x128 tile of interleaved-Ysum,
// acc = OUTA[:,k*128:+128] @ WriT[k] (Kd=128) + LAT @ WupT (Kd=192),
// columns interleaved (yv,yg); epilogue: ya = yv*silu(yg) via shfl_xor(1),
// written as packed hi/lo bf16 (feeds the out-GEMM's packed-A path).
// Grid (36, Mrows/128).
// ---------------------------------------------------------------------------
__global__ __launch_bounds__(256, 2) void stage34x_k(
    const float* __restrict__ OUTA, const float* __restrict__ Pall,
    const unsigned short* __restrict__ WriT, const unsigned short* __restrict__ WupT,
    unsigned short* __restrict__ yah)
{
    __shared__ unsigned short As[128][72];
    __shared__ unsigned short Bs[128][72];
    const int n0 = blockIdx.x * 128, m0 = blockIdx.y * 128;
    const int k  = n0 / 384;
    const int tid  = threadIdx.x;
    const int lane = tid & 63, wave = tid >> 6;
    const int wm = (wave >> 1) * 64, wn = (wave & 1) * 64;
    const int lr = lane & 15, lg = lane >> 4;
    const int sar = tid >> 1,  sac = (tid & 1) * 16;
    const int sbr = tid & 127, sbp = tid >> 7;

    f32x4 acc[4][4];
    #pragma unroll
    for (int i = 0; i < 4; i++)
        #pragma unroll
        for (int j = 0; j < 4; j++) acc[i][j] = (f32x4){0.f, 0.f, 0.f, 0.f};

    #pragma unroll
    for (int ph = 0; ph < 2; ph++) {
        const int Kd = ph ? 192 : 128;
        const float* Arow = ph ? Pall + (long)(m0 + sar) * PSTR_ + LOFF_
                               : OUTA + (long)(m0 + sar) * 1536 + k * 128;
        const unsigned short* Brow = ph
            ? WupT + (long)(n0 + sbr) * 384 + sbp * 192
            : WriT + (long)(n0 + sbr) * 256 + sbp * 128;

        for (int k0 = 0; k0 < Kd; k0 += 32) {
            {
                const float* Ap = Arow + k0 + sac;
                const float4 f0 = *(const float4*)(Ap + 0);
                const float4 f1 = *(const float4*)(Ap + 4);
                const float4 f2 = *(const float4*)(Ap + 8);
                const float4 f3 = *(const float4*)(Ap + 12);
                const float v[16] = {f0.x,f0.y,f0.z,f0.w, f1.x,f1.y,f1.z,f1.w,
                                     f2.x,f2.y,f2.z,f2.w, f3.x,f3.y,f3.z,f3.w};
                unsigned hp[8], lp[8];
                #pragma unroll
                for (int q = 0; q < 8; q++) {
                    const float a = v[2*q], b = v[2*q+1];
                    const unsigned short ha = f2bf(a), hb = f2bf(b);
                    const unsigned short la = f2bf(a - bf2f(ha));
                    const unsigned short lb = f2bf(b - bf2f(hb));
                    hp[q] = (unsigned)ha | ((unsigned)hb << 16);
                    lp[q] = (unsigned)la | ((unsigned)lb << 16);
                }
                *(uint4*)&As[sar][sac]          = make_uint4(hp[0],hp[1],hp[2],hp[3]);
                *(uint4*)&As[sar][sac + 8]      = make_uint4(hp[4],hp[5],hp[6],hp[7]);
                *(uint4*)&As[sar][32 + sac]     = make_uint4(lp[0],lp[1],lp[2],lp[3]);
                *(uint4*)&As[sar][32 + sac + 8] = make_uint4(lp[4],lp[5],lp[6],lp[7]);
            }
            {
                const unsigned short* Bq = Brow + k0;
                uint4 u0 = *(const uint4*)(Bq);
                uint4 u1 = *(const uint4*)(Bq + 8);
                uint4 u2 = *(const uint4*)(Bq + 16);
                uint4 u3 = *(const uint4*)(Bq + 24);
                *(uint4*)&Bs[sbr][sbp * 32 + 0]  = u0;
                *(uint4*)&Bs[sbr][sbp * 32 + 8]  = u1;
                *(uint4*)&Bs[sbr][sbp * 32 + 16] = u2;
                *(uint4*)&Bs[sbr][sbp * 32 + 24] = u3;
            }
            __syncthreads();
            bf16x8 af[4], bh[4], bl[4];
            #pragma unroll
            for (int f = 0; f < 4; f++) {
                af[f] = *(const bf16x8*)&As[wm + f * 16 + lr][lg * 8];
                bh[f] = *(const bf16x8*)&Bs[wn + f * 16 + lr][lg * 8];
                bl[f] = *(const bf16x8*)&Bs[wn + f * 16 + lr][32 + lg * 8];
            }
            #pragma unroll
            for (int i = 0; i < 4; i++)
                #pragma unroll
                for (int j = 0; j < 4; j++)
                    acc[i][j] = __builtin_amdgcn_mfma_f32_16x16x32_bf16(af[i], bh[j], acc[i][j], 0, 0, 0);
            #pragma unroll
            for (int i = 0; i < 4; i++)
                #pragma unroll
                for (int j = 0; j < 4; j++)
                    acc[i][j] = __builtin_amdgcn_mfma_f32_16x16x32_bf16(af[i], bl[j], acc[i][j], 0, 0, 0);
            #pragma unroll
            for (int f = 0; f < 4; f++)
                af[f] = *(const bf16x8*)&As[wm + f * 16 + lr][32 + lg * 8];
            #pragma unroll
            for (int i = 0; i < 4; i++)
                #pragma unroll
                for (int j = 0; j < 4; j++)
                    acc[i][j] = __builtin_amdgcn_mfma_f32_16x16x32_bf16(af[i], bh[j], acc[i][j], 0, 0, 0);
            __syncthreads();
        }
    }

    // epilogue: (yv,yg) interleaved in adjacent cols -> adjacent lanes
    #pragma unroll
    for (int i = 0; i < 4; i++) {
        #pragma unroll
        for (int j = 0; j < 4; j++) {
            const int gc  = n0 + wn + j * 16 + lr;
            const int yac = k * 192 + ((gc - k * 384) >> 1);
            #pragma unroll
            for (int r = 0; r < 4; r++) {
                const int gm = m0 + wm + i * 16 + lg * 4 + r;
                const float v = acc[i][j][r];
                const float p = __shfl_xor(v, 1);
                if (!(lane & 1)) {
                    const float g = p;
                    const float res = v * g * sigmoidf(g);
                    const unsigned short hh = f2bf(res);
                    const unsigned short ll = f2bf(res - bf2f(hh));
                    yah[(long)gm * 4608 + yac]        = hh;
                    yah[(long)gm * 4608 + 2304 + yac] = ll;
                }
            }
        }
    }
}

// ---------------------------------------------------------------------------
// Weight pack kernels: transposed hi/lo bf16 layouts for the MFMA GEMMs.
// ---------------------------------------------------------------------------
// WallT[1792][1536]: col n (padded from 1752), [n][k]=hi, [n][768+k]=lo
__global__ void packwallT_k(const float* __restrict__ Wm, const float* __restrict__ Wq,
                            const float* __restrict__ Wg_, const float* __restrict__ Wd,
                            unsigned short* __restrict__ WT)
{
    const int n = 1792 * 768;
    for (int t = blockIdx.x * blockDim.x + threadIdx.x; t < n;
         t += gridDim.x * blockDim.x) {
        const int c = t / 768, r = t % 768;
        float v = 0.f;
        if      (c < QOFF_) v = Wm[r * ZC_ + c];
        else if (c < GOFF_) v = Wq[r * 768 + (c - QOFF_)];
        else if (c < LOFF_) v = Wg_[r * 12 + (c - GOFF_)];
        else if (c < PSTR_) v = Wd[r * 192 + (c - LOFF_)];
        const unsigned short h = f2bf(v), l = f2bf(v - bf2f(h));
        WT[(long)c * 1536 + r]       = h;
        WT[(long)c * 1536 + 768 + r] = l;
    }
}

// WriT[(k*384+cp)][256]: interleaved col cp -> src (cp>>1)+192*(cp&1),
// rows r<64 from W_re, r>=64 from W_im; [..][rr]=hi, [..][128+rr]=lo
__global__ void packriT_k(const float* __restrict__ Wre, const float* __restrict__ Wim,
                          unsigned short* __restrict__ WT)
{
    const int n = K_ * 384 * 128;
    for (int t = blockIdx.x * blockDim.x + threadIdx.x; t < n;
         t += gridDim.x * blockDim.x) {
        const int k = t / (384 * 128);
        const int rem = t % (384 * 128);
        const int cp = rem / 128, r = rem % 128;
        const int src = (cp >> 1) + 192 * (cp & 1);
        const float v = (r < 64) ? Wre[((long)k * 64 + r) * 384 + src]
                                 : Wim[((long)k * 64 + (r - 64)) * 384 + src];
        const unsigned short h = f2bf(v), l = f2bf(v - bf2f(h));
        const long base = ((long)k * 384 + cp) * 256;
        WT[base + r]       = h;
        WT[base + 128 + r] = l;
    }
}

// WupT[c][384]: c = interleaved col of 4608, highway folded; [c][r]=hi, [c][192+r]=lo
__global__ void packupT_k(const float* __restrict__ Wup, const float* __restrict__ hw,
                          unsigned short* __restrict__ WT)
{
    const int n = 4608 * 192;
    for (int t = blockIdx.x * blockDim.x + threadIdx.x; t < n;
         t += gridDim.x * blockDim.x) {
        const int c = t / 192, r = t % 192;
        const int k = c / 384, cp = c % 384;
        const int src = (cp >> 1) + 192 * (cp & 1);
        const float v = Wup[r * 4608 + k * 384 + src] * hw[k];
        const unsigned short h = f2bf(v), l = f2bf(v - bf2f(h));
        WT[(long)c * 384 + r]       = h;
        WT[(long)c * 384 + 192 + r] = l;
    }
}

// WoutT[n][4608]: [n][k]=hi, [n][2304+k]=lo (from W_out[2304][768])
__global__ void packoutT_k(const float* __restrict__ Wout, unsigned short* __restrict__ WT)
{
    const int n = 768 * 2304;
    for (int t = blockIdx.x * blockDim.x + threadIdx.x; t < n;
         t += gridDim.x * blockDim.x) {
        const int c = t / 2304, r = t % 2304;
        const float v = Wout[(long)r * 768 + c];
        const unsigned short h = f2bf(v), l = f2bf(v - bf2f(h));
        WT[(long)c * 4608 + r]        = h;
        WT[(long)c * 4608 + 2304 + r] = l;
    }
}

// ---------------------------------------------------------------------------
// Fused scan, batch via blockIdx.z. Z read from Pall cols 0..779 (guarded
// 3-row halo). Pass1 (FINAL=false): per-(chunk,k) sums into csum[z][k][ch][129].
// Pass3 (FINAL=true): exclusive-prefix init, emit OUTA[l, k*128 + {h,64+h}].
// grid (CH2_, K_, nb), 64 threads (lane = h).
// ---------------------------------------------------------------------------
template<bool FINAL>
__global__ __launch_bounds__(64) void scan_k(
    const float* __restrict__ Pb, const float* __restrict__ convk,
    const float* __restrict__ theta, const float* __restrict__ decay,
    const float* __restrict__ ssc, const float* __restrict__ nsc,
    const float* __restrict__ bg, float* __restrict__ csumb,
    float* __restrict__ OUTAb)
{
    const int zb = blockIdx.z;
    const float* P    = Pb + (long)zb * L_ * PSTR_;
    float* csum       = csumb + (long)zb * K_ * CH2_ * 129;
    float* OUTA       = FINAL ? OUTAb + (long)zb * L_ * 1536 : nullptr;

    const int ch = blockIdx.x, k = blockIdx.y, h = threadIdx.x;
    const int col = k * 64 + h, scol = 768 + k;
    const int l0 = ch * CL2_;

    const float ck0 = convk[col],  ck1 = convk[ZC_ + col];
    const float ck2 = convk[2 * ZC_ + col], ck3 = convk[3 * ZC_ + col];
    const float cs0 = convk[scol], cs1 = convk[ZC_ + scol];
    const float cs2 = convk[2 * ZC_ + scol], cs3 = convk[3 * ZC_ + scol];

    const float th    = softplusf(theta[k * 64 + h]) + 0.001f;
    const float slope = softplusf(decay[k]);
    const float sscal = ssc[k];
    const float ns    = FINAL ? nsc[k * 64 + h] : 0.f;
    const float bgk   = FINAL ? bg[k] : 0.f;
    const int   kq    = k >> 1;

    const long cb = ((long)k * CH2_ + ch) * 129;
    float dacc = 0.f, racc = 0.f, iacc = 0.f;
    if (FINAL) { dacc = csum[cb]; racc = csum[cb + 1 + h]; iacc = csum[cb + 65 + h]; }

    for (int p = 0; p < CL2_; p++) {
        const int l = l0 + p;
        float kv, sr;
        if (l >= 3) {
            const float* zb2 = P + (long)(l - 3) * PSTR_;
            kv = ck0 * zb2[col]  + ck1 * zb2[PSTR_ + col]
               + ck2 * zb2[2 * PSTR_ + col] + ck3 * zb2[3 * PSTR_ + col];
            sr = cs0 * zb2[scol] + cs1 * zb2[PSTR_ + scol]
               + cs2 * zb2[2 * PSTR_ + scol] + cs3 * zb2[3 * PSTR_ + scol];
        } else {
            kv = ck3 * P[(long)l * PSTR_ + col];
            sr = cs3 * P[(long)l * PSTR_ + scol];
            if (l >= 1) { kv += ck2 * P[(long)(l - 1) * PSTR_ + col];
                          sr += cs2 * P[(long)(l - 1) * PSTR_ + scol]; }
            if (l >= 2) { kv += ck1 * P[(long)(l - 2) * PSTR_ + col];
                          sr += cs1 * P[(long)(l - 2) * PSTR_ + scol]; }
        }
        const float lp = fminf(fmaxf(sscal * sr, -20.f), 20.f);
        const float pw = __expf(lp - slope * (float)(L_ - 1 - l));
        const float phi = tanhf(kv) * th;
        float sn, cn; __sincosf(phi, &sn, &cn);
        dacc += pw; racc += kv * pw * cn; iacc += kv * pw * sn;

        if (FINAL) {
            const float invd = 1.f / fmaxf(dacc, 1e-4f);
            const float sre = racc * invd, sim = iacc * invd;
            const float qr = P[(long)l * PSTR_ + QOFF_ + (kq * 64 + h) * 2];
            const float qi = P[(long)l * PSTR_ + QOFF_ + (kq * 64 + h) * 2 + 1];
            const float gate = sigmoidf(P[(long)l * PSTR_ + GOFF_ + k] + bgk);
            const float s2 = ns * gate;
            OUTA[(long)l * 1536 + k * 128 + h]      = (sre * qr + sim * qi) * s2;
            OUTA[(long)l * 1536 + k * 128 + 64 + h] = (sim * qr - sre * qi) * s2;
        }
    }
    if (!FINAL) {
        if (h == 0) csum[cb] = dacc;
        csum[cb + 1 + h]  = racc;
        csum[cb + 65 + h] = iacc;
    }
}

// exclusive prefix over the 128 chunks, per (batch=blockIdx.y, k, entry 0..128)
__global__ void scan2_k(float* __restrict__ csumb)
{
    float* csum = csumb + (long)blockIdx.y * K_ * CH2_ * 129;
    const int k = blockIdx.x;
    const int t = threadIdx.x;
    if (t >= 129) return;
    float run = 0.f;
    for (int c = 0; c < CH2_; c++) {
        const long ix = ((long)k * CH2_ + c) * 129 + t;
        float v = csum[ix]; csum[ix] = run; run += v;
    }
}

// ---------------------------------------------------------------------------
extern "C" void kernel_launch(void* const* d_in, const int* in_sizes, int n_in,
                              void* d_out, int out_size, void* d_ws, size_t ws_size,
                              hipStream_t stream)
{
    float* out = (float*)d_out;   // f32 output (verified r8)
    const dim3 blk(256);

    // tripwire: input ordering/sizes
    const int expSz[16] = {12582912, 599040, 3120, 589824, 768, 12, 12,
                           294912, 294912, 768, 9216, 12, 147456, 884736,
                           12, 1769472};
    int bad = -1;
    if (n_in != 16) bad = 99;
    else { for (int i = 0; i < 16; i++) if (in_sizes[i] != expSz[i]) { bad = i; break; } }
    if (out_size != 12582912 && bad < 0) bad = 98;
    if (bad >= 0) {
        fillf_k<<<dim3(2048), blk, 0, stream>>>(out, out_size, 3000.f + bad);
        return;
    }

    const float* x     = (const float*)d_in[0];
    const float* W_mem = (const float*)d_in[1];
    const float* convk = (const float*)d_in[2];
    const float* W_q   = (const float*)d_in[3];
    const float* theta = (const float*)d_in[4];
    const float* decay = (const float*)d_in[5];
    const float* ssc   = (const float*)d_in[6];
    const float* W_re  = (const float*)d_in[7];
    const float* W_im  = (const float*)d_in[8];
    const float* nsc   = (const float*)d_in[9];
    const float* Wg    = (const float*)d_in[10];
    const float* bg    = (const float*)d_in[11];
    const float* W_dn  = (const float*)d_in[12];
    const float* W_up  = (const float*)d_in[13];
    const float* hw    = (const float*)d_in[14];
    const float* W_out = (const float*)d_in[15];

    // ---- workspace ladder: cfg0 full-batch everything; cfg1 per-batch
    //      Pall/OUTA + full yah; cfg2 everything per-batch.
    size_t o[10];
    auto plan = [&](bool fullP, bool fullY, size_t* oo) -> size_t {
        size_t off = 0;
        auto al = [&](size_t bytes) {
            size_t cur = off; off = (off + bytes + 255) & ~(size_t)255; return cur;
        };
        oo[0] = al(4);                                        // md
        oo[1] = al((size_t)B_ * K_ * CH2_ * 129 * 4);         // csum (all batches)
        oo[2] = al((size_t)(fullP ? B_ : 1) * L_ * PSTR_ * 4);// Pall
        oo[3] = al((size_t)(fullP ? B_ : 1) * L_ * 1536 * 4); // OUTA
        oo[4] = al((size_t)(fullY ? B_ : 1) * L_ * 4608 * 2); // yah (packed hi/lo)
        oo[5] = al((size_t)1792 * 1536 * 2);                  // WallT
        oo[6] = al((size_t)K_ * 384 * 256 * 2);               // WriT
        oo[7] = al((size_t)4608 * 384 * 2);                   // WupT
        oo[8] = al((size_t)768 * 4608 * 2);                   // WoutT
        return off;
    };
    const int nCfg = 3;
    const bool cfgP[nCfg] = {true, false, false};
    const bool cfgY[nCfg] = {true, true,  false};
    int cfg = -1;
    for (int c = 0; c < nCfg; c++) {
        size_t t = plan(cfgP[c], cfgY[c], o);
        if (t + 4096 <= ws_size) { cfg = c; break; }
    }
    if (cfg < 0) {
        fillf_k<<<dim3(2048), blk, 0, stream>>>(out, (long)out_size, 1000.f);
        return;
    }
    const bool FULLP = cfgP[cfg], FULLY = cfgY[cfg];

    char* ws = (char*)d_ws;
    int*            md   = (int*)(ws + o[0]);
    float*          csum = (float*)(ws + o[1]);
    float*          Pall = (float*)(ws + o[2]);
    float*          OUTA = (float*)(ws + o[3]);
    unsigned short* yah  = (unsigned short*)(ws + o[4]);
    unsigned short* WallT= (unsigned short*)(ws + o[5]);
    unsigned short* WriT = (unsigned short*)(ws + o[6]);
    unsigned short* WupT = (unsigned short*)(ws + o[7]);
    unsigned short* WoutT= (unsigned short*)(ws + o[8]);

    probe_k<<<dim3(1), dim3(64), 0, stream>>>((const unsigned*)ssc, md);
    packwallT_k<<<dim3(2048), blk, 0, stream>>>(W_mem, W_q, Wg, W_dn, WallT);
    packriT_k<<<dim3(1024), blk, 0, stream>>>(W_re, W_im, WriT);
    packupT_k<<<dim3(1024), blk, 0, stream>>>(W_up, hw, WupT);
    packoutT_k<<<dim3(2048), blk, 0, stream>>>(W_out, WoutT);

    const int nb    = FULLP ? 1 : B_;
    const int Mrows = FULLP ? B_ * L_ : L_;
    const int zGrid = FULLP ? B_ : 1;

    for (int b = 0; b < nb; b++) {
        const float* xb = x + (long)b * L_ * 768;

        // merged projection GEMM: Pall = xb @ Wall  (Z|Q|G|LAT), MFMA split-bf16
        gemmx_k<float><<<dim3(14, Mrows / 128), blk, 0, stream>>>(
            xb, WallT, Pall, 1752, 768, 768, 1752);

        // fused chunked scan, 3 passes -> OUTA
        scan_k<false><<<dim3(CH2_, K_, zGrid), dim3(64), 0, stream>>>(
            Pall, convk, theta, decay, ssc, nsc, bg, csum, nullptr);
        scan2_k<<<dim3(K_, zGrid), dim3(192), 0, stream>>>(csum);
        scan_k<true><<<dim3(CH2_, K_, zGrid), dim3(64), 0, stream>>>(
            Pall, convk, theta, decay, ssc, nsc, bg, csum, OUTA);

        // fused stage 3+4 -> ya (packed hi/lo bf16)
        unsigned short* yd = FULLY ? yah + (long)b * L_ * 4608 : yah;
        stage34x_k<<<dim3(36, Mrows / 128), blk, 0, stream>>>(
            OUTA, Pall, WriT, WupT, yd);

        if (!FULLY) {
            gemmx_k<unsigned short><<<dim3(6, L_ / 128), blk, 0, stream>>>(
                yah, WoutT, out + (long)b * L_ * 768, 768, 2304, 4608, 768);
        }
    }

    if (FULLY) {
        // one out-GEMM over all batches: (B*L) x 768, Kd=2304, packed A
        gemmx_k<unsigned short><<<dim3(6, (B_ * L_) / 128), blk, 0, stream>>>(
            yah, WoutT, out, 768, 2304, 4608, 768);
    }

    guard_k<<<dim3(2048), blk, 0, stream>>>(md, out, (long)out_size);
}

// Round 4
// 964.693 us; speedup vs baseline: 13.3752x; 1.2159x over previous
//
#include <hip/hip_runtime.h>

typedef __attribute__((ext_vector_type(8))) __bf16 bf16x8;
typedef __attribute__((ext_vector_type(4))) float f32x4;

#define B_    4
#define L_    4096
#define K_    12
#define ZC_   780        /* MEM + K */
#define CH2_  128        /* scan chunks */
#define CL2_  32         /* rows per chunk = L_/CH2_ */
#define PSTR_ 1752       /* packed projection row: 780 Z | 768 Q | 12 G | 192 LAT */
#define QOFF_ 780
#define GOFF_ 1548
#define LOFF_ 1560

__device__ __forceinline__ float softplusf(float x){ return log1pf(__expf(x)); }
__device__ __forceinline__ float sigmoidf(float x){ return 1.f / (1.f + __expf(-x)); }
// f32 -> bf16 RNE (no NaN/Inf expected in this model)
__device__ __forceinline__ unsigned short f2bf(float x){
    unsigned u = __float_as_uint(x);
    u += 0x7FFFu + ((u >> 16) & 1u);
    return (unsigned short)(u >> 16);
}
__device__ __forceinline__ float bf2f(unsigned short h){
    return __uint_as_float((unsigned)h << 16);
}

// async global->LDS, 16B per lane; LDS dest is linear (base + lane*16)
#define GLOAD16(gp, lp) __builtin_amdgcn_global_load_lds( \
    (const __attribute__((address_space(1))) unsigned int*)(gp), \
    (__attribute__((address_space(3))) unsigned int*)(lp), 16, 0, 0)

// bijective XCD swizzle (8 XCDs): contiguous wg chunk per XCD
__device__ __forceinline__ int xcd_swz(int bid, int nwg)
{
    const int q = nwg >> 3, r = nwg & 7;
    const int x = bid & 7, y = bid >> 3;
    return (x < r ? x * (q + 1) : r * (q + 1) + (x - r) * q) + y;
}

// dtype probe: score_scale == ones; f32 1.0 -> 0x3F800000
__global__ void probe_k(const unsigned* __restrict__ ss, int* __restrict__ md)
{
    if (threadIdx.x == 0 && blockIdx.x == 0) {
        unsigned w = ss[0];
        int m = 0;
        if      (w == 0x3F803F80u) m = 1;
        else if (w == 0x3C003C00u) m = 2;
        else if (w == 0x00000000u) m = 3;
        else if (w != 0x3F800000u) m = 4;
        md[0] = m;
    }
}

__global__ void fillf_k(float* __restrict__ p, long n, float v)
{
    for (long i = (long)blockIdx.x * blockDim.x + threadIdx.x; i < n;
         i += (long)gridDim.x * blockDim.x) p[i] = v;
}
__global__ void guard_k(const int* __restrict__ md, float* __restrict__ p, long n)
{
    const int m = *md;
    if (m == 0) return;
    for (long i = (long)blockIdx.x * blockDim.x + threadIdx.x; i < n;
         i += (long)gridDim.x * blockDim.x) p[i] = 4000.f + m;
}

// ---------------------------------------------------------------------------
// Split-bf16 MFMA GEMM, all-packed operands, global_load_lds staging.
// C[M,N] = A[M,Kd] @ B[Kd,N] via A_hi@B_hi + A_hi@B_lo + A_lo@B_hi.
// A packed per row: [hi(0..Kd-1) | lo(0..Kd-1)] ushorts, row stride lda.
// B packed transposed per col n: [hi | lo], row stride ldb.
// Tile 128x128, BK=32, 256 thr = 4 waves (2x2), 64x64/wave.
// LDS linear [row][64 ushort] with XOR-swizzle (cb ^= (row&7)<<4) applied on
// the READ side and inverse-applied to the global SOURCE (DMA dest linear).
// 1D grid = nTn * nTm, tn fastest, XCD-swizzled. M mult of 128, Kd mult of 32.
// ---------------------------------------------------------------------------
__global__ __launch_bounds__(256, 3) void gemmy_k(
    const unsigned short* __restrict__ A, const unsigned short* __restrict__ Bp,
    float* __restrict__ C, int N, int Kd, int lda, int ldb, int ldc, int nTn)
{
    __shared__ __align__(16) unsigned short As[128 * 64];
    __shared__ __align__(16) unsigned short Bs[128 * 64];

    const int wg = xcd_swz(blockIdx.x, gridDim.x);
    const int n0 = (wg % nTn) * 128, m0 = (wg / nTn) * 128;
    const int tid  = threadIdx.x;
    const int lane = tid & 63, wave = tid >> 6;
    const int wm = (wave >> 1) * 64, wn = (wave & 1) * 64;
    const int lr = lane & 15, lg = lane >> 4;
    const int l8 = lane >> 3, l7 = lane & 7;

    f32x4 acc[4][4];
    #pragma unroll
    for (int i = 0; i < 4; i++)
        #pragma unroll
        for (int j = 0; j < 4; j++) acc[i][j] = (f32x4){0.f, 0.f, 0.f, 0.f};

    for (int k0 = 0; k0 < Kd; k0 += 32) {
        #pragma unroll
        for (int i = 0; i < 4; i++) {           // A tile (16 KB)
            const int rl = i * 32 + wave * 8 + l8;
            const int q  = l7 ^ (rl & 7);
            const unsigned short* gp = A + (long)(m0 + rl) * lda
                + (q >= 4 ? Kd : 0) + k0 + ((q & 3) << 3);
            GLOAD16(gp, &As[i * 2048 + wave * 512 + lane * 8]);
        }
        #pragma unroll
        for (int i = 0; i < 4; i++) {           // B tile (16 KB)
            const int rl = i * 32 + wave * 8 + l8;
            const int q  = l7 ^ (rl & 7);
            const unsigned short* gp = Bp + (long)(n0 + rl) * ldb
                + (q >= 4 ? Kd : 0) + k0 + ((q & 3) << 3);
            GLOAD16(gp, &Bs[i * 2048 + wave * 512 + lane * 8]);
        }
        __syncthreads();

        bf16x8 af[4], bh[4], bl[4];
        #pragma unroll
        for (int f = 0; f < 4; f++) {
            const int ra = wm + f * 16 + lr, rb = wn + f * 16 + lr;
            const int ca = ((lg << 4) ^ ((ra & 7) << 4)) >> 1;
            const int cbh = ((lg << 4) ^ ((rb & 7) << 4)) >> 1;
            const int cbl = (((64 + (lg << 4)) ^ ((rb & 7) << 4))) >> 1;
            af[f] = *(const bf16x8*)&As[ra * 64 + ca];
            bh[f] = *(const bf16x8*)&Bs[rb * 64 + cbh];
            bl[f] = *(const bf16x8*)&Bs[rb * 64 + cbl];
        }
        #pragma unroll
        for (int i = 0; i < 4; i++)
            #pragma unroll
            for (int j = 0; j < 4; j++)
                acc[i][j] = __builtin_amdgcn_mfma_f32_16x16x32_bf16(af[i], bh[j], acc[i][j], 0, 0, 0);
        #pragma unroll
        for (int i = 0; i < 4; i++)
            #pragma unroll
            for (int j = 0; j < 4; j++)
                acc[i][j] = __builtin_amdgcn_mfma_f32_16x16x32_bf16(af[i], bl[j], acc[i][j], 0, 0, 0);
        #pragma unroll
        for (int f = 0; f < 4; f++) {
            const int ra = wm + f * 16 + lr;
            const int ca = (((64 + (lg << 4)) ^ ((ra & 7) << 4))) >> 1;
            af[f] = *(const bf16x8*)&As[ra * 64 + ca];
        }
        #pragma unroll
        for (int i = 0; i < 4; i++)
            #pragma unroll
            for (int j = 0; j < 4; j++)
                acc[i][j] = __builtin_amdgcn_mfma_f32_16x16x32_bf16(af[i], bh[j], acc[i][j], 0, 0, 0);
        __syncthreads();
    }

    // D layout: col = lane&15, row = (lane>>4)*4 + reg
    #pragma unroll
    for (int i = 0; i < 4; i++) {
        #pragma unroll
        for (int j = 0; j < 4; j++) {
            const int gn = n0 + wn + j * 16 + lr;
            if (gn < N) {
                #pragma unroll
                for (int r = 0; r < 4; r++) {
                    const int gm = m0 + wm + i * 16 + lg * 4 + r;
                    C[(long)gm * ldc + gn] = acc[i][j][r];
                }
            }
        }
    }
}

// ---------------------------------------------------------------------------
// Fused stage 3+4 (MFMA, split-bf16, gload_lds staging): per 128x128 tile of
// interleaved Ysum space, acc = OUTAh[:,k-block] @ WriT[k] (Kd=128)
//                             + LATh @ WupT (Kd=192);
// epilogue: ya = yv*silu(yg) via shfl_xor(1), written packed hi/lo bf16.
// 1D grid = 36 * nTm, tn fastest, XCD-swizzled.
// ---------------------------------------------------------------------------
__global__ __launch_bounds__(256, 3) void stage34x_k(
    const unsigned short* __restrict__ OUTAh, const unsigned short* __restrict__ LATh,
    const unsigned short* __restrict__ WriT, const unsigned short* __restrict__ WupT,
    unsigned short* __restrict__ yah)
{
    __shared__ __align__(16) unsigned short As[128 * 64];
    __shared__ __align__(16) unsigned short Bs[128 * 64];

    const int wg = xcd_swz(blockIdx.x, gridDim.x);
    const int n0 = (wg % 36) * 128, m0 = (wg / 36) * 128;
    const int k  = n0 / 384;
    const int tid  = threadIdx.x;
    const int lane = tid & 63, wave = tid >> 6;
    const int wm = (wave >> 1) * 64, wn = (wave & 1) * 64;
    const int lr = lane & 15, lg = lane >> 4;
    const int l8 = lane >> 3, l7 = lane & 7;

    f32x4 acc[4][4];
    #pragma unroll
    for (int i = 0; i < 4; i++)
        #pragma unroll
        for (int j = 0; j < 4; j++) acc[i][j] = (f32x4){0.f, 0.f, 0.f, 0.f};

    #pragma unroll
    for (int ph = 0; ph < 2; ph++) {
        const int Kd  = ph ? 192 : 128;
        const unsigned short* Ab = ph ? LATh : OUTAh + k * 256;
        const int lda = ph ? 384 : 3072;
        const unsigned short* Bb = ph ? WupT : WriT;
        const int ldb = ph ? 384 : 256;

        for (int k0 = 0; k0 < Kd; k0 += 32) {
            #pragma unroll
            for (int i = 0; i < 4; i++) {
                const int rl = i * 32 + wave * 8 + l8;
                const int q  = l7 ^ (rl & 7);
                const unsigned short* gp = Ab + (long)(m0 + rl) * lda
                    + (q >= 4 ? Kd : 0) + k0 + ((q & 3) << 3);
                GLOAD16(gp, &As[i * 2048 + wave * 512 + lane * 8]);
            }
            #pragma unroll
            for (int i = 0; i < 4; i++) {
                const int rl = i * 32 + wave * 8 + l8;
                const int q  = l7 ^ (rl & 7);
                const unsigned short* gp = Bb + (long)(n0 + rl) * ldb
                    + (q >= 4 ? Kd : 0) + k0 + ((q & 3) << 3);
                GLOAD16(gp, &Bs[i * 2048 + wave * 512 + lane * 8]);
            }
            __syncthreads();

            bf16x8 af[4], bh[4], bl[4];
            #pragma unroll
            for (int f = 0; f < 4; f++) {
                const int ra = wm + f * 16 + lr, rb = wn + f * 16 + lr;
                const int ca = ((lg << 4) ^ ((ra & 7) << 4)) >> 1;
                const int cbh = ((lg << 4) ^ ((rb & 7) << 4)) >> 1;
                const int cbl = (((64 + (lg << 4)) ^ ((rb & 7) << 4))) >> 1;
                af[f] = *(const bf16x8*)&As[ra * 64 + ca];
                bh[f] = *(const bf16x8*)&Bs[rb * 64 + cbh];
                bl[f] = *(const bf16x8*)&Bs[rb * 64 + cbl];
            }
            #pragma unroll
            for (int i = 0; i < 4; i++)
                #pragma unroll
                for (int j = 0; j < 4; j++)
                    acc[i][j] = __builtin_amdgcn_mfma_f32_16x16x32_bf16(af[i], bh[j], acc[i][j], 0, 0, 0);
            #pragma unroll
            for (int i = 0; i < 4; i++)
                #pragma unroll
                for (int j = 0; j < 4; j++)
                    acc[i][j] = __builtin_amdgcn_mfma_f32_16x16x32_bf16(af[i], bl[j], acc[i][j], 0, 0, 0);
            #pragma unroll
            for (int f = 0; f < 4; f++) {
                const int ra = wm + f * 16 + lr;
                const int ca = (((64 + (lg << 4)) ^ ((ra & 7) << 4))) >> 1;
                af[f] = *(const bf16x8*)&As[ra * 64 + ca];
            }
            #pragma unroll
            for (int i = 0; i < 4; i++)
                #pragma unroll
                for (int j = 0; j < 4; j++)
                    acc[i][j] = __builtin_amdgcn_mfma_f32_16x16x32_bf16(af[i], bh[j], acc[i][j], 0, 0, 0);
            __syncthreads();
        }
    }

    // epilogue: (yv,yg) interleaved in adjacent cols -> adjacent lanes
    #pragma unroll
    for (int i = 0; i < 4; i++) {
        #pragma unroll
        for (int j = 0; j < 4; j++) {
            const int gc  = n0 + wn + j * 16 + lr;
            const int yac = k * 192 + ((gc - k * 384) >> 1);
            #pragma unroll
            for (int r = 0; r < 4; r++) {
                const int gm = m0 + wm + i * 16 + lg * 4 + r;
                const float v = acc[i][j][r];
                const float p = __shfl_xor(v, 1);
                if (!(lane & 1)) {
                    const float g = p;
                    const float res = v * g * sigmoidf(g);
                    const unsigned short hh = f2bf(res);
                    const unsigned short ll = f2bf(res - bf2f(hh));
                    yah[(long)gm * 4608 + yac]        = hh;
                    yah[(long)gm * 4608 + 2304 + yac] = ll;
                }
            }
        }
    }
}

// ---------------------------------------------------------------------------
// Pack kernels
// ---------------------------------------------------------------------------
// xh[row][1536] = [hi 768 | lo 768] from f32 x
__global__ void packxh_k(const float* __restrict__ x, unsigned short* __restrict__ xh,
                         long rows)
{
    const long n = rows * 768;
    for (long t = (long)blockIdx.x * blockDim.x + threadIdx.x; t < n;
         t += (long)gridDim.x * blockDim.x) {
        const long r = t / 768; const int c = (int)(t % 768);
        const float v = x[t];
        const unsigned short h = f2bf(v), l = f2bf(v - bf2f(h));
        xh[r * 1536 + c]       = h;
        xh[r * 1536 + 768 + c] = l;
    }
}

// LATh[row][384] = [hi 192 | lo 192] from Pall cols LOFF_..
__global__ void packlat_k(const float* __restrict__ P, unsigned short* __restrict__ LATh,
                          long rows)
{
    const long n = rows * 192;
    for (long t = (long)blockIdx.x * blockDim.x + threadIdx.x; t < n;
         t += (long)gridDim.x * blockDim.x) {
        const long r = t / 192; const int c = (int)(t % 192);
        const float v = P[r * PSTR_ + LOFF_ + c];
        const unsigned short h = f2bf(v), l = f2bf(v - bf2f(h));
        LATh[r * 384 + c]       = h;
        LATh[r * 384 + 192 + c] = l;
    }
}

// WallT[1792][1536]: col n (padded from 1752), [n][k]=hi, [n][768+k]=lo
__global__ void packwallT_k(const float* __restrict__ Wm, const float* __restrict__ Wq,
                            const float* __restrict__ Wg_, const float* __restrict__ Wd,
                            unsigned short* __restrict__ WT)
{
    const int n = 1792 * 768;
    for (int t = blockIdx.x * blockDim.x + threadIdx.x; t < n;
         t += gridDim.x * blockDim.x) {
        const int c = t / 768, r = t % 768;
        float v = 0.f;
        if      (c < QOFF_) v = Wm[r * ZC_ + c];
        else if (c < GOFF_) v = Wq[r * 768 + (c - QOFF_)];
        else if (c < LOFF_) v = Wg_[r * 12 + (c - GOFF_)];
        else if (c < PSTR_) v = Wd[r * 192 + (c - LOFF_)];
        const unsigned short h = f2bf(v), l = f2bf(v - bf2f(h));
        WT[(long)c * 1536 + r]       = h;
        WT[(long)c * 1536 + 768 + r] = l;
    }
}

// WriT[(k*384+cp)][256]: interleaved col cp -> src (cp>>1)+192*(cp&1),
// rows r<64 from W_re, r>=64 from W_im; [..][rr]=hi, [..][128+rr]=lo
__global__ void packriT_k(const float* __restrict__ Wre, const float* __restrict__ Wim,
                          unsigned short* __restrict__ WT)
{
    const int n = K_ * 384 * 128;
    for (int t = blockIdx.x * blockDim.x + threadIdx.x; t < n;
         t += gridDim.x * blockDim.x) {
        const int k = t / (384 * 128);
        const int rem = t % (384 * 128);
        const int cp = rem / 128, r = rem % 128;
        const int src = (cp >> 1) + 192 * (cp & 1);
        const float v = (r < 64) ? Wre[((long)k * 64 + r) * 384 + src]
                                 : Wim[((long)k * 64 + (r - 64)) * 384 + src];
        const unsigned short h = f2bf(v), l = f2bf(v - bf2f(h));
        const long base = ((long)k * 384 + cp) * 256;
        WT[base + r]       = h;
        WT[base + 128 + r] = l;
    }
}

// WupT[c][384]: interleaved col of 4608, highway folded; [c][r]=hi, [c][192+r]=lo
__global__ void packupT_k(const float* __restrict__ Wup, const float* __restrict__ hw,
                          unsigned short* __restrict__ WT)
{
    const int n = 4608 * 192;
    for (int t = blockIdx.x * blockDim.x + threadIdx.x; t < n;
         t += gridDim.x * blockDim.x) {
        const int c = t / 192, r = t % 192;
        const int k = c / 384, cp = c % 384;
        const int src = (cp >> 1) + 192 * (cp & 1);
        const float v = Wup[r * 4608 + k * 384 + src] * hw[k];
        const unsigned short h = f2bf(v), l = f2bf(v - bf2f(h));
        WT[(long)c * 384 + r]       = h;
        WT[(long)c * 384 + 192 + r] = l;
    }
}

// WoutT[n][4608]: [n][k]=hi, [n][2304+k]=lo (from W_out[2304][768])
__global__ void packoutT_k(const float* __restrict__ Wout, unsigned short* __restrict__ WT)
{
    const int n = 768 * 2304;
    for (int t = blockIdx.x * blockDim.x + threadIdx.x; t < n;
         t += gridDim.x * blockDim.x) {
        const int c = t / 2304, r = t % 2304;
        const float v = Wout[(long)r * 768 + c];
        const unsigned short h = f2bf(v), l = f2bf(v - bf2f(h));
        WT[(long)c * 4608 + r]        = h;
        WT[(long)c * 4608 + 2304 + r] = l;
    }
}

// ---------------------------------------------------------------------------
// Fused scan, batch via blockIdx.z. Z read from Pall cols 0..779 (guarded
// 3-row halo). Pass1 (FINAL=false): per-(chunk,k) sums into csum[z][k][ch][129].
// Pass3 (FINAL=true): exclusive-prefix init, emit OUTAh packed hi/lo:
// per k-block of 256 ushorts: [h]=re_hi, [64+h]=im_hi, [128+h]=re_lo, [192+h]=im_lo.
// grid (CH2_, K_, nb), 64 threads (lane = h).
// ---------------------------------------------------------------------------
template<bool FINAL>
__global__ __launch_bounds__(64) void scan_k(
    const float* __restrict__ Pb, const float* __restrict__ convk,
    const float* __restrict__ theta, const float* __restrict__ decay,
    const float* __restrict__ ssc, const float* __restrict__ nsc,
    const float* __restrict__ bg, float* __restrict__ csumb,
    unsigned short* __restrict__ OUTAhb)
{
    const int zb = blockIdx.z;
    const float* P          = Pb + (long)zb * L_ * PSTR_;
    float* csum             = csumb + (long)zb * K_ * CH2_ * 129;
    unsigned short* OUTAh   = FINAL ? OUTAhb + (long)zb * L_ * 3072 : nullptr;

    const int ch = blockIdx.x, k = blockIdx.y, h = threadIdx.x;
    const int col = k * 64 + h, scol = 768 + k;
    const int l0 = ch * CL2_;

    const float ck0 = convk[col],  ck1 = convk[ZC_ + col];
    const float ck2 = convk[2 * ZC_ + col], ck3 = convk[3 * ZC_ + col];
    const float cs0 = convk[scol], cs1 = convk[ZC_ + scol];
    const float cs2 = convk[2 * ZC_ + scol], cs3 = convk[3 * ZC_ + scol];

    const float th    = softplusf(theta[k * 64 + h]) + 0.001f;
    const float slope = softplusf(decay[k]);
    const float sscal = ssc[k];
    const float ns    = FINAL ? nsc[k * 64 + h] : 0.f;
    const float bgk   = FINAL ? bg[k] : 0.f;
    const int   kq    = k >> 1;

    const long cb = ((long)k * CH2_ + ch) * 129;
    float dacc = 0.f, racc = 0.f, iacc = 0.f;
    if (FINAL) { dacc = csum[cb]; racc = csum[cb + 1 + h]; iacc = csum[cb + 65 + h]; }

    for (int p = 0; p < CL2_; p++) {
        const int l = l0 + p;
        float kv, sr;
        if (l >= 3) {
            const float* zb2 = P + (long)(l - 3) * PSTR_;
            kv = ck0 * zb2[col]  + ck1 * zb2[PSTR_ + col]
               + ck2 * zb2[2 * PSTR_ + col] + ck3 * zb2[3 * PSTR_ + col];
            sr = cs0 * zb2[scol] + cs1 * zb2[PSTR_ + scol]
               + cs2 * zb2[2 * PSTR_ + scol] + cs3 * zb2[3 * PSTR_ + scol];
        } else {
            kv = ck3 * P[(long)l * PSTR_ + col];
            sr = cs3 * P[(long)l * PSTR_ + scol];
            if (l >= 1) { kv += ck2 * P[(long)(l - 1) * PSTR_ + col];
                          sr += cs2 * P[(long)(l - 1) * PSTR_ + scol]; }
            if (l >= 2) { kv += ck1 * P[(long)(l - 2) * PSTR_ + col];
                          sr += cs1 * P[(long)(l - 2) * PSTR_ + scol]; }
        }
        const float lp = fminf(fmaxf(sscal * sr, -20.f), 20.f);
        const float pw = __expf(lp - slope * (float)(L_ - 1 - l));
        const float phi = tanhf(kv) * th;
        float sn, cn; __sincosf(phi, &sn, &cn);
        dacc += pw; racc += kv * pw * cn; iacc += kv * pw * sn;

        if (FINAL) {
            const float invd = 1.f / fmaxf(dacc, 1e-4f);
            const float sre = racc * invd, sim = iacc * invd;
            const float qr = P[(long)l * PSTR_ + QOFF_ + (kq * 64 + h) * 2];
            const float qi = P[(long)l * PSTR_ + QOFF_ + (kq * 64 + h) * 2 + 1];
            const float gate = sigmoidf(P[(long)l * PSTR_ + GOFF_ + k] + bgk);
            const float s2 = ns * gate;
            const float vre = (sre * qr + sim * qi) * s2;
            const float vim = (sim * qr - sre * qi) * s2;
            const unsigned short hre = f2bf(vre), him = f2bf(vim);
            const unsigned short lre = f2bf(vre - bf2f(hre));
            const unsigned short lim = f2bf(vim - bf2f(him));
            unsigned short* orow = OUTAh + (long)l * 3072 + k * 256;
            orow[h]       = hre;
            orow[64 + h]  = him;
            orow[128 + h] = lre;
            orow[192 + h] = lim;
        }
    }
    if (!FINAL) {
        if (h == 0) csum[cb] = dacc;
        csum[cb + 1 + h]  = racc;
        csum[cb + 65 + h] = iacc;
    }
}

// exclusive prefix over the 128 chunks, per (batch=blockIdx.y, k, entry 0..128)
__global__ void scan2_k(float* __restrict__ csumb)
{
    float* csum = csumb + (long)blockIdx.y * K_ * CH2_ * 129;
    const int k = blockIdx.x;
    const int t = threadIdx.x;
    if (t >= 129) return;
    float run = 0.f;
    for (int c = 0; c < CH2_; c++) {
        const long ix = ((long)k * CH2_ + c) * 129 + t;
        float v = csum[ix]; csum[ix] = run; run += v;
    }
}

// ---------------------------------------------------------------------------
extern "C" void kernel_launch(void* const* d_in, const int* in_sizes, int n_in,
                              void* d_out, int out_size, void* d_ws, size_t ws_size,
                              hipStream_t stream)
{
    float* out = (float*)d_out;   // f32 output (verified r8)
    const dim3 blk(256);

    // tripwire: input ordering/sizes
    const int expSz[16] = {12582912, 599040, 3120, 589824, 768, 12, 12,
                           294912, 294912, 768, 9216, 12, 147456, 884736,
                           12, 1769472};
    int bad = -1;
    if (n_in != 16) bad = 99;
    else { for (int i = 0; i < 16; i++) if (in_sizes[i] != expSz[i]) { bad = i; break; } }
    if (out_size != 12582912 && bad < 0) bad = 98;
    if (bad >= 0) {
        fillf_k<<<dim3(2048), blk, 0, stream>>>(out, out_size, 3000.f + bad);
        return;
    }

    const float* x     = (const float*)d_in[0];
    const float* W_mem = (const float*)d_in[1];
    const float* convk = (const float*)d_in[2];
    const float* W_q   = (const float*)d_in[3];
    const float* theta = (const float*)d_in[4];
    const float* decay = (const float*)d_in[5];
    const float* ssc   = (const float*)d_in[6];
    const float* W_re  = (const float*)d_in[7];
    const float* W_im  = (const float*)d_in[8];
    const float* nsc   = (const float*)d_in[9];
    const float* Wg    = (const float*)d_in[10];
    const float* bg    = (const float*)d_in[11];
    const float* W_dn  = (const float*)d_in[12];
    const float* W_up  = (const float*)d_in[13];
    const float* hw    = (const float*)d_in[14];
    const float* W_out = (const float*)d_in[15];

    // ---- workspace ladder: cfg0 full-batch everything; cfg1 per-batch
    //      activations + full yah; cfg2 everything per-batch.
    size_t o[12];
    auto plan = [&](bool fullP, bool fullY, size_t* oo) -> size_t {
        const long rp = fullP ? (long)B_ * L_ : L_;
        const long ry = fullY ? (long)B_ * L_ : L_;
        size_t off = 0;
        auto al = [&](size_t bytes) {
            size_t cur = off; off = (off + bytes + 255) & ~(size_t)255; return cur;
        };
        oo[0]  = al(4);                                   // md
        oo[1]  = al((size_t)B_ * K_ * CH2_ * 129 * 4);    // csum (all batches)
        oo[2]  = al((size_t)rp * 1536 * 2);               // xh (packed hi/lo)
        oo[3]  = al((size_t)rp * PSTR_ * 4);              // Pall (f32)
        oo[4]  = al((size_t)rp * 3072 * 2);               // OUTAh (packed)
        oo[5]  = al((size_t)rp * 384 * 2);                // LATh (packed)
        oo[6]  = al((size_t)ry * 4608 * 2);               // yah (packed)
        oo[7]  = al((size_t)1792 * 1536 * 2);             // WallT
        oo[8]  = al((size_t)K_ * 384 * 256 * 2);          // WriT
        oo[9]  = al((size_t)4608 * 384 * 2);              // WupT
        oo[10] = al((size_t)768 * 4608 * 2);              // WoutT
        return off;
    };
    const int nCfg = 3;
    const bool cfgP[nCfg] = {true, false, false};
    const bool cfgY[nCfg] = {true, true,  false};
    int cfg = -1;
    for (int c = 0; c < nCfg; c++) {
        size_t t = plan(cfgP[c], cfgY[c], o);
        if (t + 4096 <= ws_size) { cfg = c; break; }
    }
    if (cfg < 0) {
        fillf_k<<<dim3(2048), blk, 0, stream>>>(out, (long)out_size, 1000.f);
        return;
    }
    const bool FULLP = cfgP[cfg], FULLY = cfgY[cfg];

    char* ws = (char*)d_ws;
    int*            md    = (int*)(ws + o[0]);
    float*          csum  = (float*)(ws + o[1]);
    unsigned short* xh    = (unsigned short*)(ws + o[2]);
    float*          Pall  = (float*)(ws + o[3]);
    unsigned short* OUTAh = (unsigned short*)(ws + o[4]);
    unsigned short* LATh  = (unsigned short*)(ws + o[5]);
    unsigned short* yah   = (unsigned short*)(ws + o[6]);
    unsigned short* WallT = (unsigned short*)(ws + o[7]);
    unsigned short* WriT  = (unsigned short*)(ws + o[8]);
    unsigned short* WupT  = (unsigned short*)(ws + o[9]);
    unsigned short* WoutT = (unsigned short*)(ws + o[10]);

    probe_k<<<dim3(1), dim3(64), 0, stream>>>((const unsigned*)ssc, md);
    packwallT_k<<<dim3(2048), blk, 0, stream>>>(W_mem, W_q, Wg, W_dn, WallT);
    packriT_k<<<dim3(1024), blk, 0, stream>>>(W_re, W_im, WriT);
    packupT_k<<<dim3(1024), blk, 0, stream>>>(W_up, hw, WupT);
    packoutT_k<<<dim3(2048), blk, 0, stream>>>(W_out, WoutT);

    const int nb    = FULLP ? 1 : B_;
    const long Mr   = FULLP ? (long)B_ * L_ : L_;
    const int nTm   = (int)(Mr / 128);
    const int zGrid = FULLP ? B_ : 1;

    for (int b = 0; b < nb; b++) {
        const float* xb = x + (long)b * L_ * 768;

        // pack x -> hi/lo, then merged projection GEMM: Pall = x @ Wall
        packxh_k<<<dim3(4096), blk, 0, stream>>>(xb, xh, Mr);
        gemmy_k<<<dim3(14 * nTm), blk, 0, stream>>>(
            xh, WallT, Pall, 1752, 768, 1536, 1536, 1752, 14);
        packlat_k<<<dim3(2048), blk, 0, stream>>>(Pall, LATh, Mr);

        // fused chunked scan, 3 passes -> OUTAh (packed)
        scan_k<false><<<dim3(CH2_, K_, zGrid), dim3(64), 0, stream>>>(
            Pall, convk, theta, decay, ssc, nsc, bg, csum, nullptr);
        scan2_k<<<dim3(K_, zGrid), dim3(192), 0, stream>>>(csum);
        scan_k<true><<<dim3(CH2_, K_, zGrid), dim3(64), 0, stream>>>(
            Pall, convk, theta, decay, ssc, nsc, bg, csum, OUTAh);

        // fused stage 3+4 -> ya (packed hi/lo bf16)
        unsigned short* yd = (FULLY && !FULLP) ? yah + (long)b * L_ * 4608 : yah;
        stage34x_k<<<dim3(36 * nTm), blk, 0, stream>>>(
            OUTAh, LATh, WriT, WupT, yd);

        if (!FULLY) {
            gemmy_k<<<dim3(6 * nTm), blk, 0, stream>>>(
                yah, WoutT, out + (long)b * L_ * 768, 768, 2304, 4608, 4608, 768, 6);
        }
    }

    if (FULLY) {
        // one out-GEMM over all batches: (B*L) x 768, Kd=2304
        gemmy_k<<<dim3(6 * (int)((long)B_ * L_ / 128)), blk, 0, stream>>>(
            yah, WoutT, out, 768, 2304, 4608, 4608, 768, 6);
    }

    guard_k<<<dim3(2048), blk, 0, stream>>>(md, out, (long)out_size);
}